// Round 7
// baseline (361.518 us; speedup 1.0000x reference)
//
#include <hip/hip_runtime.h>
#include <math.h>

// ============================================================================
// BitNet transformer block, MI355X (gfx950).  Round 7.
// R6 -> R7:
//  (a) attn VALU diet: raw v_exp_f32 (was libm exp2f ~7 inst), diagonal mask
//      split into uniform branch (16 cmp+sel only on diag iter), s_setprio(1)
//      around MFMA clusters (T5).
//  (b) gemm_ffn: w1+w2 GEMM + silu + group-64 quant fused in one kernel
//      (epilogue writes zq directly; y1y2 buffer + silu kernel deleted,
//      -128MB HBM traffic).
// ws layout (MB = 2^20), peak ~89 MB:
//   0..32    sign weights (wq@0,wk@2,wv@4,wo@6, w1@8,w2@16, w3@24)
//   32..33   alpha partials (7*256 f32); alphas (7 f32) at +16KB
//   33..49   Vt bf16 [16][64][4096] (live transpose->attn), then x1 fp32
//   49..57   hq bf16 (rmsnorm->gemm inputs)
//   57..89   qkv bf16 [4096,3072] (->attn); then zq bf16 [4096,4096]
//   81..89   yb bf16 (attn->wo gemm; inside qkv slot after attn reads it...
//            kept at 81MB, distinct from zq@57..89?  zq spans 57..89 ->
//            OVERLAP with yb@81: yb dead after wo-gemm which runs BEFORE
//            gemm_ffn writes zq. Safe.)
// ============================================================================

typedef unsigned short u16;
typedef __attribute__((ext_vector_type(4))) float f32x4;
typedef __attribute__((ext_vector_type(4))) unsigned short u16x4;
typedef __attribute__((ext_vector_type(8))) unsigned short u16x8;
typedef __attribute__((ext_vector_type(8))) __bf16 bf16x8;

#define DEV static __device__ __forceinline__

DEV float bf2f(u16 u) { union { unsigned i; float f; } c; c.i = ((unsigned)u) << 16; return c.f; }
DEV u16 f2bf(float f) { __bf16 b = (__bf16)f; return __builtin_bit_cast(u16, b); }
DEV float fexp2(float x) { float r; asm("v_exp_f32 %0, %1" : "=v"(r) : "v"(x)); return r; }

DEV void gload16(const void* g, void* l) {
  __builtin_amdgcn_global_load_lds((__attribute__((address_space(1))) void*)g,
                                   (__attribute__((address_space(3))) void*)l,
                                   16, 0, 0);
}

// ---------------------------------------------------------------------------
// Weight prep: sign(w) -> bf16 {+1,-1,0}, block-partial sums of |w|.
// ---------------------------------------------------------------------------
__global__ __launch_bounds__(256) void convert_sign_all(
    const float* __restrict__ w0, const float* __restrict__ w1,
    const float* __restrict__ w2, const float* __restrict__ w3,
    const float* __restrict__ w4, const float* __restrict__ w5,
    const float* __restrict__ w6, u16* __restrict__ sgn_base,
    float* __restrict__ partial) {
  __shared__ float red[4];
  const int wi = blockIdx.y;
  const float* srcs[7] = {w0, w1, w2, w3, w4, w5, w6};
  const size_t offs[7] = {0, 1048576, 2097152, 3145728, 4194304, 8388608, 12582912};
  const float* w = srcs[wi];
  u16* sgn = sgn_base + offs[wi];
  const int n4 = (wi < 4) ? 262144 : 1048576;

  float s = 0.f;
  for (int i = blockIdx.x * 256 + threadIdx.x; i < n4; i += 256 * 256) {
    f32x4 v = ((const f32x4*)w)[i];
    u16x4 o;
#pragma unroll
    for (int j = 0; j < 4; ++j) {
      float f = v[j];
      o[j] = f > 0.f ? (u16)0x3F80 : (f < 0.f ? (u16)0xBF80 : (u16)0);
      s += fabsf(f);
    }
    ((u16x4*)sgn)[i] = o;
  }
#pragma unroll
  for (int off = 32; off >= 1; off >>= 1) s += __shfl_xor(s, off);
  if ((threadIdx.x & 63) == 0) red[threadIdx.x >> 6] = s;
  __syncthreads();
  if (threadIdx.x == 0)
    partial[wi * 256 + blockIdx.x] = red[0] + red[1] + red[2] + red[3];
}

__global__ __launch_bounds__(256) void finalize_alpha(
    const float* __restrict__ partial, float* __restrict__ alphas) {
  __shared__ float red[4];
  int wi = blockIdx.x;  // 0..6
  float v = partial[wi * 256 + threadIdx.x];
#pragma unroll
  for (int off = 32; off >= 1; off >>= 1) v += __shfl_xor(v, off);
  if ((threadIdx.x & 63) == 0) red[threadIdx.x >> 6] = v;
  __syncthreads();
  if (threadIdx.x == 0)
    alphas[wi] = (red[0] + red[1] + red[2] + red[3]) *
                 (wi < 4 ? (1.f / 1048576.f) : (1.f / 4194304.f));
}

// ---------------------------------------------------------------------------
// RMSNorm + act_quant (group 64). One block per row of 1024.
// ---------------------------------------------------------------------------
__global__ __launch_bounds__(256) void rmsnorm_quant(
    const float* __restrict__ x, const float* __restrict__ g, u16* __restrict__ out) {
  __shared__ float red[4];
  const int row = blockIdx.x, t = threadIdx.x;
  f32x4 v = ((const f32x4*)(x + (size_t)row * 1024))[t];
  float ss = v[0] * v[0] + v[1] * v[1] + v[2] * v[2] + v[3] * v[3];
#pragma unroll
  for (int off = 32; off >= 1; off >>= 1) ss += __shfl_xor(ss, off);
  if ((t & 63) == 0) red[t >> 6] = ss;
  __syncthreads();
  float tot = red[0] + red[1] + red[2] + red[3];
  float rinv = rsqrtf(tot * (1.f / 1024.f) + 1e-6f);
  f32x4 gg = ((const f32x4*)g)[t];
  float n[4];
#pragma unroll
  for (int j = 0; j < 4; ++j) n[j] = v[j] * rinv * gg[j];
  float gm = fmaxf(fmaxf(fabsf(n[0]), fabsf(n[1])), fmaxf(fabsf(n[2]), fabsf(n[3])));
#pragma unroll
  for (int off = 1; off <= 8; off <<= 1) gm = fmaxf(gm, __shfl_xor(gm, off));
  float s = fmaxf(gm, 1e-5f) / 127.0f;
  u16x4 o;
#pragma unroll
  for (int j = 0; j < 4; ++j) {
    float q = fminf(fmaxf(rintf(n[j] / s), -127.f), 127.f) * s;
    o[j] = f2bf(q);
  }
  ((u16x4*)out)[(size_t)row * 256 + t] = o;
}

// ---------------------------------------------------------------------------
// V transpose: qkv[:,2048+h*64 .. +63] -> Vt[h][d][t]  ([16][64][4096] bf16).
// ---------------------------------------------------------------------------
__global__ __launch_bounds__(256) void transpose_v(
    const u16* __restrict__ qkv, u16* __restrict__ Vt) {
  __shared__ u16 T[64][65];
  const int tt = blockIdx.x, h = blockIdx.y, tid = threadIdx.x;
#pragma unroll
  for (int i = 0; i < 2; ++i) {
    int idx = i * 2048 + tid * 8;
    int trow = idx >> 6, dcol = idx & 63;
    u16x8 v = *(const u16x8*)(qkv + (size_t)(tt * 64 + trow) * 3072 + 2048 + h * 64 + dcol);
#pragma unroll
    for (int j = 0; j < 8; ++j) T[dcol + j][trow] = v[j];
  }
  __syncthreads();
#pragma unroll
  for (int i = 0; i < 2; ++i) {
    int idx = i * 2048 + tid * 8;
    int drow = idx >> 6, tcol = idx & 63;
    u16x8 v;
#pragma unroll
    for (int j = 0; j < 8; ++j) v[j] = T[drow][tcol + j];
    *(u16x8*)(Vt + ((size_t)h * 64 + drow) * 4096 + tt * 64 + tcol) = v;
  }
}

// ---------------------------------------------------------------------------
// GEMM: C[M,N] = alpha[bcol>>ashift] * (A[M,K] @ B[N,K]^T) (+res).
// BMx128 tile, BK=64, 4 waves, global_load_lds w=16, XOR swizzle.
// ---------------------------------------------------------------------------
template <bool RES, int BM>
__global__ __launch_bounds__(256) void gemm_bt(
    const u16* __restrict__ A, const u16* __restrict__ B,
    const float* __restrict__ alpha, int ashift, const float* __restrict__ res,
    void* __restrict__ Cout, int M, int N, int K) {
  constexpr int NI = (BM == 128) ? 4 : 2;
  constexpr int WNE = (BM == 128) ? 64 : 32;
  __shared__ u16 As[BM * 64];
  __shared__ u16 Bs[128 * 64];
  const int tid = threadIdx.x;
  const int l = tid & 63, w = tid >> 6;
  const int wm = (BM == 128) ? (w >> 1) : 0;
  const int wn = (BM == 128) ? (w & 1) : w;
  const int lr = l & 15, lg = l >> 4;
  const int xorv = (l & 7) << 4;
  const int brow = blockIdx.y * BM;
  const int bcol = blockIdx.x * 128;
  const int src_chunk = (l & 7) ^ (l >> 3);
  const int rl = w * 8 + (l >> 3);

  f32x4 acc[4][NI];
#pragma unroll
  for (int i = 0; i < 4; ++i)
#pragma unroll
    for (int j = 0; j < NI; ++j) acc[i][j] = (f32x4){0.f, 0.f, 0.f, 0.f};

  const char* Ag = (const char*)A;
  const char* Bg = (const char*)B;
  const int nkt = K >> 6;
  for (int kt = 0; kt < nkt; ++kt) {
    __syncthreads();
    const size_t kb = (size_t)kt * 128 + src_chunk * 16;
#pragma unroll
    for (int it = 0; it < BM / 32; ++it)
      gload16(Ag + (size_t)(brow + it * 32 + rl) * (size_t)(K * 2) + kb,
              &As[(it * 32 + w * 8) * 64]);
#pragma unroll
    for (int it = 0; it < 4; ++it)
      gload16(Bg + (size_t)(bcol + it * 32 + rl) * (size_t)(K * 2) + kb,
              &Bs[(it * 32 + w * 8) * 64]);
    __syncthreads();

    bf16x8 af[4][2], bfr[NI][2];
#pragma unroll
    for (int mi = 0; mi < 4; ++mi)
#pragma unroll
      for (int ks = 0; ks < 2; ++ks) {
        int row = wm * 64 + mi * 16 + lr;
        af[mi][ks] = *(const bf16x8*)((const char*)As + row * 128 + ((ks * 64 + lg * 16) ^ xorv));
      }
#pragma unroll
    for (int ni = 0; ni < NI; ++ni)
#pragma unroll
      for (int ks = 0; ks < 2; ++ks) {
        int row = wn * WNE + ni * 16 + lr;
        bfr[ni][ks] = *(const bf16x8*)((const char*)Bs + row * 128 + ((ks * 64 + lg * 16) ^ xorv));
      }
#pragma unroll
    for (int ks = 0; ks < 2; ++ks)
#pragma unroll
      for (int mi = 0; mi < 4; ++mi)
#pragma unroll
        for (int ni = 0; ni < NI; ++ni)
          acc[mi][ni] = __builtin_amdgcn_mfma_f32_16x16x32_bf16(
              af[mi][ks], bfr[ni][ks], acc[mi][ni], 0, 0, 0);
  }

  const float scale = alpha[bcol >> ashift];
#pragma unroll
  for (int mi = 0; mi < 4; ++mi)
#pragma unroll
    for (int ni = 0; ni < NI; ++ni)
#pragma unroll
      for (int r = 0; r < 4; ++r) {
        int row = brow + wm * 64 + mi * 16 + lg * 4 + r;
        int col = bcol + wn * WNE + ni * 16 + lr;
        float vv = acc[mi][ni][r] * scale;
        if (RES)
          ((float*)Cout)[(size_t)row * N + col] = res[(size_t)row * N + col] + vv;
        else
          ((u16*)Cout)[(size_t)row * N + col] = f2bf(vv);
      }
}

// ---------------------------------------------------------------------------
// Fused FFN GEMM: y1 = hq@W1^T, y2 = hq@W2^T (same 128x128 tile cols of ff),
// epilogue z = silu(a1*y1)*(a2*y2), group-64 quant along ff, write zq bf16.
// ---------------------------------------------------------------------------
__global__ __launch_bounds__(256) void gemm_ffn(
    const u16* __restrict__ A, const u16* __restrict__ B1,
    const u16* __restrict__ B2, const float* __restrict__ alpha2,
    u16* __restrict__ zq) {
  __shared__ u16 As[128 * 64];
  __shared__ u16 B1s[128 * 64];
  __shared__ u16 B2s[128 * 64];
  const int tid = threadIdx.x;
  const int l = tid & 63, w = tid >> 6;
  const int wm = w >> 1, wn = w & 1;
  const int lr = l & 15, lg = l >> 4;
  const int xorv = (l & 7) << 4;
  const int brow = blockIdx.y * 128;
  const int bcol = blockIdx.x * 128;  // ff-dim tile (N = 4096)
  const int src_chunk = (l & 7) ^ (l >> 3);
  const int rl = w * 8 + (l >> 3);
  const int K = 1024;

  f32x4 acc1[4][4], acc2[4][4];
#pragma unroll
  for (int i = 0; i < 4; ++i)
#pragma unroll
    for (int j = 0; j < 4; ++j) {
      acc1[i][j] = (f32x4){0.f, 0.f, 0.f, 0.f};
      acc2[i][j] = (f32x4){0.f, 0.f, 0.f, 0.f};
    }

  for (int kt = 0; kt < 16; ++kt) {
    __syncthreads();
    const size_t kb = (size_t)kt * 128 + src_chunk * 16;
#pragma unroll
    for (int it = 0; it < 4; ++it) {
      gload16((const char*)A + (size_t)(brow + it * 32 + rl) * 2048 + kb,
              &As[(it * 32 + w * 8) * 64]);
      gload16((const char*)B1 + (size_t)(bcol + it * 32 + rl) * 2048 + kb,
              &B1s[(it * 32 + w * 8) * 64]);
      gload16((const char*)B2 + (size_t)(bcol + it * 32 + rl) * 2048 + kb,
              &B2s[(it * 32 + w * 8) * 64]);
    }
    __syncthreads();

    bf16x8 af[4][2], bfr[4][2];
#pragma unroll
    for (int mi = 0; mi < 4; ++mi)
#pragma unroll
      for (int ks = 0; ks < 2; ++ks) {
        int row = wm * 64 + mi * 16 + lr;
        af[mi][ks] = *(const bf16x8*)((const char*)As + row * 128 + ((ks * 64 + lg * 16) ^ xorv));
      }
    // W1 pass
#pragma unroll
    for (int ni = 0; ni < 4; ++ni)
#pragma unroll
      for (int ks = 0; ks < 2; ++ks) {
        int row = wn * 64 + ni * 16 + lr;
        bfr[ni][ks] = *(const bf16x8*)((const char*)B1s + row * 128 + ((ks * 64 + lg * 16) ^ xorv));
      }
#pragma unroll
    for (int ks = 0; ks < 2; ++ks)
#pragma unroll
      for (int mi = 0; mi < 4; ++mi)
#pragma unroll
        for (int ni = 0; ni < 4; ++ni)
          acc1[mi][ni] = __builtin_amdgcn_mfma_f32_16x16x32_bf16(
              af[mi][ks], bfr[ni][ks], acc1[mi][ni], 0, 0, 0);
    // W2 pass
#pragma unroll
    for (int ni = 0; ni < 4; ++ni)
#pragma unroll
      for (int ks = 0; ks < 2; ++ks) {
        int row = wn * 64 + ni * 16 + lr;
        bfr[ni][ks] = *(const bf16x8*)((const char*)B2s + row * 128 + ((ks * 64 + lg * 16) ^ xorv));
      }
#pragma unroll
    for (int ks = 0; ks < 2; ++ks)
#pragma unroll
      for (int mi = 0; mi < 4; ++mi)
#pragma unroll
        for (int ni = 0; ni < 4; ++ni)
          acc2[mi][ni] = __builtin_amdgcn_mfma_f32_16x16x32_bf16(
              af[mi][ks], bfr[ni][ks], acc2[mi][ni], 0, 0, 0);
  }

  // epilogue: silu(a1*y1)*(a2*y2), group-64 quant over (ni, lr), write bf16
  const float a1 = alpha2[0], a2 = alpha2[1];
  const float L2E = 1.4426950408889634f;
#pragma unroll
  for (int mi = 0; mi < 4; ++mi)
#pragma unroll
    for (int r = 0; r < 4; ++r) {
      float zz[4];
      float gm = 0.f;
#pragma unroll
      for (int ni = 0; ni < 4; ++ni) {
        float y1 = acc1[mi][ni][r] * a1;
        float y2 = acc2[mi][ni][r] * a2;
        float sg = y1 / (1.f + fexp2(-L2E * y1));
        zz[ni] = sg * y2;
        gm = fmaxf(gm, fabsf(zz[ni]));
      }
#pragma unroll
      for (int off = 1; off <= 8; off <<= 1) gm = fmaxf(gm, __shfl_xor(gm, off));
      float gmc = fmaxf(gm, 1e-5f);
      float s = gmc * (1.f / 127.f);
      float inv = 127.f / gmc;
      int row = brow + wm * 64 + mi * 16 + lg * 4 + r;
#pragma unroll
      for (int ni = 0; ni < 4; ++ni) {
        int col = bcol + wn * 64 + ni * 16 + lr;
        float q = fminf(fmaxf(rintf(zz[ni] * inv), -127.f), 127.f) * s;
        zq[(size_t)row * 4096 + col] = f2bf(q);
      }
    }
}

// ---------------------------------------------------------------------------
// Causal flash attention + act_quant epilogue.  SWAPPED-OPERAND form.
// Grid (16 heads, 64 q-tiles): qt = y<32 ? y : 95-y (balanced round-robin).
// Raw v_exp_f32 softmax, uniform-branched diag mask, setprio MFMA clusters.
// ---------------------------------------------------------------------------
__global__ __launch_bounds__(256) void attn_kernel(
    const u16* __restrict__ QKV, const u16* __restrict__ Vt, u16* __restrict__ Y) {
  __shared__ u16 Ks[2][64 * 64];  // [k-token 64][d 64] swizzled
  __shared__ u16 Vs[2][64 * 64];  // [d 64][k-token 64] swizzled
  __shared__ u16 Ps[4][16 * 64];  // per-wave P^T [q 16][token 64] swizzled

  const int tid = threadIdx.x;
  const int l = tid & 63, w = tid >> 6;
  const int lr = l & 15, lg = l >> 4;
  const int xorv = (l & 7) << 4;
  const int h = blockIdx.x;
  const int y = blockIdx.y;
  const int qt = (y < 32) ? y : (95 - y);
  const int src_chunk = (l & 7) ^ (l >> 3);
  const int rl = w * 8 + (l >> 3);
  const float SC = 0.18033688f;  // 0.125 * log2(e)

  const int qrow0 = qt * 64 + w * 16;
  const int nkt = qt + 1;

  bf16x8 qf[2];
#pragma unroll
  for (int ks = 0; ks < 2; ++ks)
    qf[ks] = __builtin_bit_cast(
        bf16x8, *(const u16x8*)(QKV + (size_t)(qrow0 + lr) * 3072 +
                                h * 64 + ks * 32 + lg * 8));

  f32x4 O[4];  // O^T: lane holds O[q=lr][d = ni*16 + lg*4 + r]
#pragma unroll
  for (int ni = 0; ni < 4; ++ni) O[ni] = (f32x4){0.f, 0.f, 0.f, 0.f};
  float m_ = -3e38f, lsum = 0.f;

  auto STAGE = [&](int buf, int kt) {
#pragma unroll
    for (int it = 0; it < 2; ++it) {
      int krow = kt * 64 + it * 32 + rl;
      gload16((const char*)QKV + ((size_t)krow * 3072 + 1024 + h * 64) * 2 + src_chunk * 16,
              &Ks[buf][(it * 32 + w * 8) * 64]);
      int drow = it * 32 + rl;
      gload16((const char*)Vt + (((size_t)h * 64 + drow) * 4096 + kt * 64) * 2 + src_chunk * 16,
              &Vs[buf][(it * 32 + w * 8) * 64]);
    }
  };

  STAGE(0, 0);
#pragma unroll 1
  for (int kt = 0; kt < nkt; ++kt) {
    const int cur = kt & 1;
    if (kt + 1 < nkt) {
      STAGE(cur ^ 1, kt + 1);
      asm volatile("s_waitcnt vmcnt(4)" ::: "memory");
    } else {
      asm volatile("s_waitcnt vmcnt(0)" ::: "memory");
    }
    __builtin_amdgcn_s_barrier();
    __builtin_amdgcn_sched_barrier(0);

    const char* kbase = (const char*)&Ks[cur][0];
    const char* vbase = (const char*)&Vs[cur][0];

    // S^T[ni] = mfma(K, Q)
    f32x4 S[4];
    __builtin_amdgcn_s_setprio(1);
#pragma unroll
    for (int ni = 0; ni < 4; ++ni) {
      S[ni] = (f32x4){0.f, 0.f, 0.f, 0.f};
#pragma unroll
      for (int ks = 0; ks < 2; ++ks) {
        bf16x8 kf = *(const bf16x8*)(kbase + (ni * 16 + lr) * 128 +
                                     ((ks * 64 + lg * 16) ^ xorv));
        S[ni] = __builtin_amdgcn_mfma_f32_16x16x32_bf16(kf, qf[ks], S[ni], 0, 0, 0);
      }
    }
    __builtin_amdgcn_s_setprio(0);

    // scale to exp2 domain; mask only on the (uniform) diagonal iteration
#pragma unroll
    for (int ni = 0; ni < 4; ++ni)
#pragma unroll
      for (int r = 0; r < 4; ++r) S[ni][r] *= SC;
    if (kt == qt) {
#pragma unroll
      for (int ni = 0; ni < 4; ++ni)
#pragma unroll
        for (int r = 0; r < 4; ++r)
          if ((ni * 16 + lg * 4 + r) > (w * 16 + lr)) S[ni][r] = -3e38f;
    }

    // online softmax (lane owns its q-row)
    float nm = -3e38f;
#pragma unroll
    for (int ni = 0; ni < 4; ++ni)
#pragma unroll
      for (int r = 0; r < 4; ++r) nm = fmaxf(nm, S[ni][r]);
    nm = fmaxf(nm, __shfl_xor(nm, 16));
    nm = fmaxf(nm, __shfl_xor(nm, 32));
    if (__ballot(nm > m_ + 8.f)) {  // T13 defer-rescale
      float mn = fmaxf(m_, nm);
      float fac = fexp2(m_ - mn);
      m_ = mn;
      lsum *= fac;
#pragma unroll
      for (int ni = 0; ni < 4; ++ni) O[ni] *= fac;
    }
    float rs = 0.f;
#pragma unroll
    for (int ni = 0; ni < 4; ++ni)
#pragma unroll
      for (int r = 0; r < 4; ++r) {
        float pv = fexp2(S[ni][r] - m_);  // bounded by 2^8 under defer
        S[ni][r] = pv;
        rs += pv;
      }
    rs += __shfl_xor(rs, 16);
    rs += __shfl_xor(rs, 32);
    lsum += rs;

    // P^T -> per-wave LDS, packed b64
#pragma unroll
    for (int ni = 0; ni < 4; ++ni) {
      u16x4 pk;
#pragma unroll
      for (int r = 0; r < 4; ++r) pk[r] = f2bf(S[ni][r]);
      *(u16x4*)((char*)&Ps[w][0] + lr * 128 + ((ni * 32 + lg * 8) ^ xorv)) = pk;
    }
    bf16x8 pt[2];
#pragma unroll
    for (int ks = 0; ks < 2; ++ks)
      pt[ks] = *(const bf16x8*)((const char*)&Ps[w][0] + lr * 128 +
                                ((ks * 64 + lg * 16) ^ xorv));

    // O^T[ni] += mfma(V^T, P^T)
    __builtin_amdgcn_s_setprio(1);
#pragma unroll
    for (int ni = 0; ni < 4; ++ni) {
#pragma unroll
      for (int ks = 0; ks < 2; ++ks) {
        bf16x8 vf = *(const bf16x8*)(vbase + (ni * 16 + lr) * 128 +
                                     ((ks * 64 + lg * 16) ^ xorv));
        O[ni] = __builtin_amdgcn_mfma_f32_16x16x32_bf16(vf, pt[ks], O[ni], 0, 0, 0);
      }
    }
    __builtin_amdgcn_s_setprio(0);
    asm volatile("" ::: "memory");
    __builtin_amdgcn_s_barrier();
  }

  // epilogue: normalize + act_quant
  float rinv = 1.f / lsum;
  float o[4][4];
  float gm = 0.f;
#pragma unroll
  for (int ni = 0; ni < 4; ++ni)
#pragma unroll
    for (int r = 0; r < 4; ++r) {
      o[ni][r] = O[ni][r] * rinv;
      gm = fmaxf(gm, fabsf(o[ni][r]));
    }
  gm = fmaxf(gm, __shfl_xor(gm, 16));
  gm = fmaxf(gm, __shfl_xor(gm, 32));
  float gmc = fmaxf(gm, 1e-5f);
  float s = gmc * (1.f / 127.f);
  float inv = 127.f / gmc;
#pragma unroll
  for (int ni = 0; ni < 4; ++ni) {
    u16x4 ov;
#pragma unroll
    for (int r = 0; r < 4; ++r) {
      float q = fminf(fmaxf(rintf(o[ni][r] * inv), -127.f), 127.f) * s;
      ov[r] = f2bf(q);
    }
    *(u16x4*)(Y + (size_t)(qrow0 + lr) * 1024 + h * 64 + ni * 16 + lg * 4) = ov;
  }
}

// ---------------------------------------------------------------------------
extern "C" void kernel_launch(void* const* d_in, const int* in_sizes, int n_in,
                              void* d_out, int out_size, void* d_ws, size_t ws_size,
                              hipStream_t stream) {
  const float* x  = (const float*)d_in[0];
  const float* wq = (const float*)d_in[1];
  const float* wk = (const float*)d_in[2];
  const float* wv = (const float*)d_in[3];
  const float* wo = (const float*)d_in[4];
  const float* w1 = (const float*)d_in[5];
  const float* w2 = (const float*)d_in[6];
  const float* w3 = (const float*)d_in[7];
  const float* g1 = (const float*)d_in[8];
  const float* g2 = (const float*)d_in[9];

  char* ws = (char*)d_ws;
  const size_t MB = 1024 * 1024;
  u16* sgn   = (u16*)ws;
  u16* sWq   = (u16*)(ws + 0 * MB);
  u16* sWo   = (u16*)(ws + 6 * MB);
  u16* sW1   = (u16*)(ws + 8 * MB);
  u16* sW2   = (u16*)(ws + 16 * MB);
  u16* sW3   = (u16*)(ws + 24 * MB);
  float* partial = (float*)(ws + 32 * MB);
  float* alphas  = (float*)(ws + 32 * MB + 16384);
  u16* Vt    = (u16*)(ws + 33 * MB);   // dead before x1 written
  float* x1  = (float*)(ws + 33 * MB); // fp32 [4096,1024]
  u16* hq    = (u16*)(ws + 49 * MB);   // bf16 [4096,1024]
  u16* qkv   = (u16*)(ws + 57 * MB);   // bf16 [4096,3072]
  u16* yb    = (u16*)(ws + 81 * MB);   // bf16 [4096,1024]
  u16* zq    = (u16*)(ws + 57 * MB);   // bf16 [4096,4096] (qkv,yb dead)

  // weight prep
  convert_sign_all<<<dim3(256, 7), 256, 0, stream>>>(wq, wk, wv, wo, w1, w2, w3,
                                                     sgn, partial);
  finalize_alpha<<<7, 256, 0, stream>>>(partial, alphas);

  // attention branch
  rmsnorm_quant<<<4096, 256, 0, stream>>>(x, g1, hq);
  gemm_bt<false, 128><<<dim3(24, 32), 256, 0, stream>>>(hq, sWq, alphas, 10, nullptr,
                                                        qkv, 4096, 3072, 1024);
  transpose_v<<<dim3(64, 16), 256, 0, stream>>>(qkv, Vt);
  attn_kernel<<<dim3(16, 64), 256, 0, stream>>>(qkv, Vt, yb);
  gemm_bt<true, 64><<<dim3(8, 64), 256, 0, stream>>>(yb, sWo, alphas + 3, 31, x,
                                                     x1, 4096, 1024, 1024);
  // FFN branch
  rmsnorm_quant<<<4096, 256, 0, stream>>>(x1, g2, hq);
  gemm_ffn<<<dim3(32, 32), 256, 0, stream>>>(hq, sW1, sW2, alphas + 4, zq);
  gemm_bt<true, 64><<<dim3(8, 64), 256, 0, stream>>>(zq, sW3, alphas + 6, 31, x1,
                                                     (float*)d_out, 4096, 1024, 4096);
}

// Round 8
// 339.167 us; speedup vs baseline: 1.0659x; 1.0659x over previous
//
#include <hip/hip_runtime.h>
#include <math.h>

// ============================================================================
// BitNet transformer block, MI355X (gfx950).  Round 8.
// R7 -> R8: gemm_ffn rebuilt. R7's 3-buffer version (48KB LDS) dropped to
// 3 blocks/CU and regressed (133us vs 90 for separate). Now: W1/W2 rows
// INTERLEAVED at weight-prep time (sW12[8192,1024]: rows 128g+u = W1 64g+u
// for u<64, W2 64g+u-64 for u>=64) -> standard 2-buffer 128x128 gemm tile
// computes y1 and y2 of the SAME z-column group; epilogue exchanges y2
// through the (reused) 32KB staging LDS and writes silu(y1)*y2 quantized.
// Same occupancy/staging as proven gemm_bt.
// ws layout (MB = 2^20):
//   0..32    sign weights (wq@0,wk@2,wv@4,wo@6, w12 interleaved@8..24, w3@24)
//   32..33   alpha partials (7*256 f32); alphas (7 f32) at +16KB
//   33..49   Vt bf16 [16][64][4096] (transpose->attn), then x1 fp32
//   49..57   hq bf16
//   57..89   qkv bf16 [4096,3072] (->attn), then zq bf16 [4096,4096]
//   81..89   yb bf16 (dead before zq written)
// ============================================================================

typedef unsigned short u16;
typedef __attribute__((ext_vector_type(4))) float f32x4;
typedef __attribute__((ext_vector_type(4))) unsigned short u16x4;
typedef __attribute__((ext_vector_type(8))) unsigned short u16x8;
typedef __attribute__((ext_vector_type(8))) __bf16 bf16x8;

#define DEV static __device__ __forceinline__

DEV float bf2f(u16 u) { union { unsigned i; float f; } c; c.i = ((unsigned)u) << 16; return c.f; }
DEV u16 f2bf(float f) { __bf16 b = (__bf16)f; return __builtin_bit_cast(u16, b); }
DEV float fexp2(float x) { float r; asm("v_exp_f32 %0, %1" : "=v"(r) : "v"(x)); return r; }

DEV void gload16(const void* g, void* l) {
  __builtin_amdgcn_global_load_lds((__attribute__((address_space(1))) void*)g,
                                   (__attribute__((address_space(3))) void*)l,
                                   16, 0, 0);
}

// ---------------------------------------------------------------------------
// Weight prep: sign(w) -> bf16 {+1,-1,0}, block-partial |w| sums.
// wi 4/5 (w1/w2) write into ONE interleaved buffer at +8MB (row remap).
// ---------------------------------------------------------------------------
__global__ __launch_bounds__(256) void convert_sign_all(
    const float* __restrict__ w0, const float* __restrict__ w1,
    const float* __restrict__ w2, const float* __restrict__ w3,
    const float* __restrict__ w4, const float* __restrict__ w5,
    const float* __restrict__ w6, u16* __restrict__ sgn_base,
    float* __restrict__ partial) {
  __shared__ float red[4];
  const int wi = blockIdx.y;
  const float* srcs[7] = {w0, w1, w2, w3, w4, w5, w6};
  const size_t offs[7] = {0, 1048576, 2097152, 3145728, 4194304, 4194304, 12582912};
  const float* w = srcs[wi];
  u16* sgn = sgn_base + offs[wi];
  const int n4 = (wi < 4) ? 262144 : 1048576;
  const bool ilv = (wi == 4) || (wi == 5);
  const int ilv_add = (wi == 5) ? 64 : 0;

  float s = 0.f;
  for (int i = blockIdx.x * 256 + threadIdx.x; i < n4; i += 256 * 256) {
    f32x4 v = ((const f32x4*)w)[i];
    u16x4 o;
#pragma unroll
    for (int j = 0; j < 4; ++j) {
      float f = v[j];
      o[j] = f > 0.f ? (u16)0x3F80 : (f < 0.f ? (u16)0xBF80 : (u16)0);
      s += fabsf(f);
    }
    size_t di = i;
    if (ilv) {
      int e = i << 2;                 // element index
      int row = e >> 10, col = e & 1023;
      int dst = ((row >> 6) << 7) + ilv_add + (row & 63);
      di = ((size_t)dst << 8) + (col >> 2);
    }
    ((u16x4*)sgn)[di] = o;
  }
#pragma unroll
  for (int off = 32; off >= 1; off >>= 1) s += __shfl_xor(s, off);
  if ((threadIdx.x & 63) == 0) red[threadIdx.x >> 6] = s;
  __syncthreads();
  if (threadIdx.x == 0)
    partial[wi * 256 + blockIdx.x] = red[0] + red[1] + red[2] + red[3];
}

__global__ __launch_bounds__(256) void finalize_alpha(
    const float* __restrict__ partial, float* __restrict__ alphas) {
  __shared__ float red[4];
  int wi = blockIdx.x;  // 0..6
  float v = partial[wi * 256 + threadIdx.x];
#pragma unroll
  for (int off = 32; off >= 1; off >>= 1) v += __shfl_xor(v, off);
  if ((threadIdx.x & 63) == 0) red[threadIdx.x >> 6] = v;
  __syncthreads();
  if (threadIdx.x == 0)
    alphas[wi] = (red[0] + red[1] + red[2] + red[3]) *
                 (wi < 4 ? (1.f / 1048576.f) : (1.f / 4194304.f));
}

// ---------------------------------------------------------------------------
// RMSNorm + act_quant (group 64). One block per row of 1024.
// ---------------------------------------------------------------------------
__global__ __launch_bounds__(256) void rmsnorm_quant(
    const float* __restrict__ x, const float* __restrict__ g, u16* __restrict__ out) {
  __shared__ float red[4];
  const int row = blockIdx.x, t = threadIdx.x;
  f32x4 v = ((const f32x4*)(x + (size_t)row * 1024))[t];
  float ss = v[0] * v[0] + v[1] * v[1] + v[2] * v[2] + v[3] * v[3];
#pragma unroll
  for (int off = 32; off >= 1; off >>= 1) ss += __shfl_xor(ss, off);
  if ((t & 63) == 0) red[t >> 6] = ss;
  __syncthreads();
  float tot = red[0] + red[1] + red[2] + red[3];
  float rinv = rsqrtf(tot * (1.f / 1024.f) + 1e-6f);
  f32x4 gg = ((const f32x4*)g)[t];
  float n[4];
#pragma unroll
  for (int j = 0; j < 4; ++j) n[j] = v[j] * rinv * gg[j];
  float gm = fmaxf(fmaxf(fabsf(n[0]), fabsf(n[1])), fmaxf(fabsf(n[2]), fabsf(n[3])));
#pragma unroll
  for (int off = 1; off <= 8; off <<= 1) gm = fmaxf(gm, __shfl_xor(gm, off));
  float s = fmaxf(gm, 1e-5f) / 127.0f;
  u16x4 o;
#pragma unroll
  for (int j = 0; j < 4; ++j) {
    float q = fminf(fmaxf(rintf(n[j] / s), -127.f), 127.f) * s;
    o[j] = f2bf(q);
  }
  ((u16x4*)out)[(size_t)row * 256 + t] = o;
}

// ---------------------------------------------------------------------------
// V transpose: qkv[:,2048+h*64 .. +63] -> Vt[h][d][t]  ([16][64][4096] bf16).
// ---------------------------------------------------------------------------
__global__ __launch_bounds__(256) void transpose_v(
    const u16* __restrict__ qkv, u16* __restrict__ Vt) {
  __shared__ u16 T[64][65];
  const int tt = blockIdx.x, h = blockIdx.y, tid = threadIdx.x;
#pragma unroll
  for (int i = 0; i < 2; ++i) {
    int idx = i * 2048 + tid * 8;
    int trow = idx >> 6, dcol = idx & 63;
    u16x8 v = *(const u16x8*)(qkv + (size_t)(tt * 64 + trow) * 3072 + 2048 + h * 64 + dcol);
#pragma unroll
    for (int j = 0; j < 8; ++j) T[dcol + j][trow] = v[j];
  }
  __syncthreads();
#pragma unroll
  for (int i = 0; i < 2; ++i) {
    int idx = i * 2048 + tid * 8;
    int drow = idx >> 6, tcol = idx & 63;
    u16x8 v;
#pragma unroll
    for (int j = 0; j < 8; ++j) v[j] = T[drow][tcol + j];
    *(u16x8*)(Vt + ((size_t)h * 64 + drow) * 4096 + tt * 64 + tcol) = v;
  }
}

// ---------------------------------------------------------------------------
// GEMM: C[M,N] = alpha[bcol>>ashift] * (A[M,K] @ B[N,K]^T) (+res).
// BMx128 tile, BK=64, 4 waves, global_load_lds w=16, XOR swizzle.
// ---------------------------------------------------------------------------
template <bool RES, int BM>
__global__ __launch_bounds__(256) void gemm_bt(
    const u16* __restrict__ A, const u16* __restrict__ B,
    const float* __restrict__ alpha, int ashift, const float* __restrict__ res,
    void* __restrict__ Cout, int M, int N, int K) {
  constexpr int NI = (BM == 128) ? 4 : 2;
  constexpr int WNE = (BM == 128) ? 64 : 32;
  __shared__ u16 As[BM * 64];
  __shared__ u16 Bs[128 * 64];
  const int tid = threadIdx.x;
  const int l = tid & 63, w = tid >> 6;
  const int wm = (BM == 128) ? (w >> 1) : 0;
  const int wn = (BM == 128) ? (w & 1) : w;
  const int lr = l & 15, lg = l >> 4;
  const int xorv = (l & 7) << 4;
  const int brow = blockIdx.y * BM;
  const int bcol = blockIdx.x * 128;
  const int src_chunk = (l & 7) ^ (l >> 3);
  const int rl = w * 8 + (l >> 3);

  f32x4 acc[4][NI];
#pragma unroll
  for (int i = 0; i < 4; ++i)
#pragma unroll
    for (int j = 0; j < NI; ++j) acc[i][j] = (f32x4){0.f, 0.f, 0.f, 0.f};

  const char* Ag = (const char*)A;
  const char* Bg = (const char*)B;
  const int nkt = K >> 6;
  for (int kt = 0; kt < nkt; ++kt) {
    __syncthreads();
    const size_t kb = (size_t)kt * 128 + src_chunk * 16;
#pragma unroll
    for (int it = 0; it < BM / 32; ++it)
      gload16(Ag + (size_t)(brow + it * 32 + rl) * (size_t)(K * 2) + kb,
              &As[(it * 32 + w * 8) * 64]);
#pragma unroll
    for (int it = 0; it < 4; ++it)
      gload16(Bg + (size_t)(bcol + it * 32 + rl) * (size_t)(K * 2) + kb,
              &Bs[(it * 32 + w * 8) * 64]);
    __syncthreads();

    bf16x8 af[4][2], bfr[NI][2];
#pragma unroll
    for (int mi = 0; mi < 4; ++mi)
#pragma unroll
      for (int ks = 0; ks < 2; ++ks) {
        int row = wm * 64 + mi * 16 + lr;
        af[mi][ks] = *(const bf16x8*)((const char*)As + row * 128 + ((ks * 64 + lg * 16) ^ xorv));
      }
#pragma unroll
    for (int ni = 0; ni < NI; ++ni)
#pragma unroll
      for (int ks = 0; ks < 2; ++ks) {
        int row = wn * WNE + ni * 16 + lr;
        bfr[ni][ks] = *(const bf16x8*)((const char*)Bs + row * 128 + ((ks * 64 + lg * 16) ^ xorv));
      }
#pragma unroll
    for (int ks = 0; ks < 2; ++ks)
#pragma unroll
      for (int mi = 0; mi < 4; ++mi)
#pragma unroll
        for (int ni = 0; ni < NI; ++ni)
          acc[mi][ni] = __builtin_amdgcn_mfma_f32_16x16x32_bf16(
              af[mi][ks], bfr[ni][ks], acc[mi][ni], 0, 0, 0);
  }

  const float scale = alpha[bcol >> ashift];
#pragma unroll
  for (int mi = 0; mi < 4; ++mi)
#pragma unroll
    for (int ni = 0; ni < NI; ++ni)
#pragma unroll
      for (int r = 0; r < 4; ++r) {
        int row = brow + wm * 64 + mi * 16 + lg * 4 + r;
        int col = bcol + wn * WNE + ni * 16 + lr;
        float vv = acc[mi][ni][r] * scale;
        if (RES)
          ((float*)Cout)[(size_t)row * N + col] = res[(size_t)row * N + col] + vv;
        else
          ((u16*)Cout)[(size_t)row * N + col] = f2bf(vv);
      }
}

// ---------------------------------------------------------------------------
// Fused FFN GEMM over INTERLEAVED W12 [8192,1024] (tile = z-col group g):
// waves wn=0 accumulate y1 (W1 rows), wn=1 accumulate y2 (W2 rows).
// Epilogue: y2 -> LDS (reused staging, XOR-swizzled), wn=0 computes
// silu(a1*y1)*(a2*y2), group-64 quant (this tile's 64 ff cols), writes zq.
// LDS = 32KB (same as gemm_bt) -> 5 blocks/CU.
// ---------------------------------------------------------------------------
__global__ __launch_bounds__(256) void gemm_ffn(
    const u16* __restrict__ A, const u16* __restrict__ B12,
    const float* __restrict__ alpha2, u16* __restrict__ zq) {
  __shared__ char smem[32768];
  u16* As = (u16*)smem;               // [128][64] staging
  u16* Bs = (u16*)(smem + 16384);     // [128][64] staging
  float* ex = (float*)smem;           // epilogue: [64 col][128 row] f32

  const int tid = threadIdx.x;
  const int l = tid & 63, w = tid >> 6;
  const int wm = w >> 1, wn = w & 1;
  const int lr = l & 15, lg = l >> 4;
  const int xorv = (l & 7) << 4;
  const int brow = blockIdx.y * 128;
  const int bcol = blockIdx.x * 128;  // interleaved W12 rows; z group = blockIdx.x
  const int src_chunk = (l & 7) ^ (l >> 3);
  const int rl = w * 8 + (l >> 3);

  f32x4 acc[4][4];
#pragma unroll
  for (int i = 0; i < 4; ++i)
#pragma unroll
    for (int j = 0; j < 4; ++j) acc[i][j] = (f32x4){0.f, 0.f, 0.f, 0.f};

  for (int kt = 0; kt < 16; ++kt) {
    __syncthreads();
    const size_t kb = (size_t)kt * 128 + src_chunk * 16;
#pragma unroll
    for (int it = 0; it < 4; ++it) {
      gload16((const char*)A + (size_t)(brow + it * 32 + rl) * 2048 + kb,
              &As[(it * 32 + w * 8) * 64]);
      gload16((const char*)B12 + (size_t)(bcol + it * 32 + rl) * 2048 + kb,
              &Bs[(it * 32 + w * 8) * 64]);
    }
    __syncthreads();

    bf16x8 af[4][2], bfr[4][2];
#pragma unroll
    for (int mi = 0; mi < 4; ++mi)
#pragma unroll
      for (int ks = 0; ks < 2; ++ks) {
        int row = wm * 64 + mi * 16 + lr;
        af[mi][ks] = *(const bf16x8*)((const char*)As + row * 128 + ((ks * 64 + lg * 16) ^ xorv));
      }
#pragma unroll
    for (int ni = 0; ni < 4; ++ni)
#pragma unroll
      for (int ks = 0; ks < 2; ++ks) {
        int row = wn * 64 + ni * 16 + lr;
        bfr[ni][ks] = *(const bf16x8*)((const char*)Bs + row * 128 + ((ks * 64 + lg * 16) ^ xorv));
      }
#pragma unroll
    for (int ks = 0; ks < 2; ++ks)
#pragma unroll
      for (int mi = 0; mi < 4; ++mi)
#pragma unroll
        for (int ni = 0; ni < 4; ++ni)
          acc[mi][ni] = __builtin_amdgcn_mfma_f32_16x16x32_bf16(
              af[mi][ks], bfr[ni][ks], acc[mi][ni], 0, 0, 0);
  }

  // ---- epilogue ----
  const float a1 = alpha2[0], a2 = alpha2[1];
  const float L2E = 1.4426950408889634f;
  __syncthreads();  // staging reads complete; reuse smem as f32 exchange
  if (wn == 1) {    // y2 waves: write a2*acc to ex[col][row^swz]
#pragma unroll
    for (int mi = 0; mi < 4; ++mi)
#pragma unroll
      for (int ni = 0; ni < 4; ++ni) {
        int col = ni * 16 + lr;
        int row0 = wm * 64 + mi * 16 + lg * 4;
        int rs = row0 ^ ((col & 3) << 3);  // 4-way instead of 16-way conflicts
        f32x4 t = acc[mi][ni];
        t[0] *= a2; t[1] *= a2; t[2] *= a2; t[3] *= a2;
        *(f32x4*)&ex[col * 128 + rs] = t;
      }
  }
  __syncthreads();
  if (wn == 0) {    // y1 waves: z = silu(a1*y1)*y2, quant, store
#pragma unroll
    for (int mi = 0; mi < 4; ++mi) {
      f32x4 y2v[4];
#pragma unroll
      for (int ni = 0; ni < 4; ++ni) {
        int col = ni * 16 + lr;
        int row0 = wm * 64 + mi * 16 + lg * 4;
        y2v[ni] = *(const f32x4*)&ex[col * 128 + (row0 ^ ((col & 3) << 3))];
      }
#pragma unroll
      for (int r = 0; r < 4; ++r) {
        float zz[4];
        float gm = 0.f;
#pragma unroll
        for (int ni = 0; ni < 4; ++ni) {
          float y1 = acc[mi][ni][r] * a1;
          float sg = y1 / (1.f + fexp2(-L2E * y1));
          zz[ni] = sg * y2v[ni][r];
          gm = fmaxf(gm, fabsf(zz[ni]));
        }
#pragma unroll
        for (int off = 1; off <= 8; off <<= 1) gm = fmaxf(gm, __shfl_xor(gm, off));
        float gmc = fmaxf(gm, 1e-5f);
        float s = gmc * (1.f / 127.f);
        float inv = 127.f / gmc;
        int row = brow + wm * 64 + mi * 16 + lg * 4 + r;
#pragma unroll
        for (int ni = 0; ni < 4; ++ni) {
          int col = blockIdx.x * 64 + ni * 16 + lr;
          float q = fminf(fmaxf(rintf(zz[ni] * inv), -127.f), 127.f) * s;
          zq[(size_t)row * 4096 + col] = f2bf(q);
        }
      }
    }
  }
}

// ---------------------------------------------------------------------------
// Causal flash attention + act_quant epilogue.  SWAPPED-OPERAND form.
// Grid (16 heads, 64 q-tiles): qt = y<32 ? y : 95-y (balanced round-robin).
// Raw v_exp_f32 softmax, uniform-branched diag mask, setprio MFMA clusters.
// ---------------------------------------------------------------------------
__global__ __launch_bounds__(256) void attn_kernel(
    const u16* __restrict__ QKV, const u16* __restrict__ Vt, u16* __restrict__ Y) {
  __shared__ u16 Ks[2][64 * 64];  // [k-token 64][d 64] swizzled
  __shared__ u16 Vs[2][64 * 64];  // [d 64][k-token 64] swizzled
  __shared__ u16 Ps[4][16 * 64];  // per-wave P^T [q 16][token 64] swizzled

  const int tid = threadIdx.x;
  const int l = tid & 63, w = tid >> 6;
  const int lr = l & 15, lg = l >> 4;
  const int xorv = (l & 7) << 4;
  const int h = blockIdx.x;
  const int y = blockIdx.y;
  const int qt = (y < 32) ? y : (95 - y);
  const int src_chunk = (l & 7) ^ (l >> 3);
  const int rl = w * 8 + (l >> 3);
  const float SC = 0.18033688f;  // 0.125 * log2(e)

  const int qrow0 = qt * 64 + w * 16;
  const int nkt = qt + 1;

  bf16x8 qf[2];
#pragma unroll
  for (int ks = 0; ks < 2; ++ks)
    qf[ks] = __builtin_bit_cast(
        bf16x8, *(const u16x8*)(QKV + (size_t)(qrow0 + lr) * 3072 +
                                h * 64 + ks * 32 + lg * 8));

  f32x4 O[4];  // O^T: lane holds O[q=lr][d = ni*16 + lg*4 + r]
#pragma unroll
  for (int ni = 0; ni < 4; ++ni) O[ni] = (f32x4){0.f, 0.f, 0.f, 0.f};
  float m_ = -3e38f, lsum = 0.f;

  auto STAGE = [&](int buf, int kt) {
#pragma unroll
    for (int it = 0; it < 2; ++it) {
      int krow = kt * 64 + it * 32 + rl;
      gload16((const char*)QKV + ((size_t)krow * 3072 + 1024 + h * 64) * 2 + src_chunk * 16,
              &Ks[buf][(it * 32 + w * 8) * 64]);
      int drow = it * 32 + rl;
      gload16((const char*)Vt + (((size_t)h * 64 + drow) * 4096 + kt * 64) * 2 + src_chunk * 16,
              &Vs[buf][(it * 32 + w * 8) * 64]);
    }
  };

  STAGE(0, 0);
#pragma unroll 1
  for (int kt = 0; kt < nkt; ++kt) {
    const int cur = kt & 1;
    if (kt + 1 < nkt) {
      STAGE(cur ^ 1, kt + 1);
      asm volatile("s_waitcnt vmcnt(4)" ::: "memory");
    } else {
      asm volatile("s_waitcnt vmcnt(0)" ::: "memory");
    }
    __builtin_amdgcn_s_barrier();
    __builtin_amdgcn_sched_barrier(0);

    const char* kbase = (const char*)&Ks[cur][0];
    const char* vbase = (const char*)&Vs[cur][0];

    // S^T[ni] = mfma(K, Q)
    f32x4 S[4];
    __builtin_amdgcn_s_setprio(1);
#pragma unroll
    for (int ni = 0; ni < 4; ++ni) {
      S[ni] = (f32x4){0.f, 0.f, 0.f, 0.f};
#pragma unroll
      for (int ks = 0; ks < 2; ++ks) {
        bf16x8 kf = *(const bf16x8*)(kbase + (ni * 16 + lr) * 128 +
                                     ((ks * 64 + lg * 16) ^ xorv));
        S[ni] = __builtin_amdgcn_mfma_f32_16x16x32_bf16(kf, qf[ks], S[ni], 0, 0, 0);
      }
    }
    __builtin_amdgcn_s_setprio(0);

    // scale to exp2 domain; mask only on the (uniform) diagonal iteration
#pragma unroll
    for (int ni = 0; ni < 4; ++ni)
#pragma unroll
      for (int r = 0; r < 4; ++r) S[ni][r] *= SC;
    if (kt == qt) {
#pragma unroll
      for (int ni = 0; ni < 4; ++ni)
#pragma unroll
        for (int r = 0; r < 4; ++r)
          if ((ni * 16 + lg * 4 + r) > (w * 16 + lr)) S[ni][r] = -3e38f;
    }

    // online softmax (lane owns its q-row)
    float nm = -3e38f;
#pragma unroll
    for (int ni = 0; ni < 4; ++ni)
#pragma unroll
      for (int r = 0; r < 4; ++r) nm = fmaxf(nm, S[ni][r]);
    nm = fmaxf(nm, __shfl_xor(nm, 16));
    nm = fmaxf(nm, __shfl_xor(nm, 32));
    if (__ballot(nm > m_ + 8.f)) {  // T13 defer-rescale
      float mn = fmaxf(m_, nm);
      float fac = fexp2(m_ - mn);
      m_ = mn;
      lsum *= fac;
#pragma unroll
      for (int ni = 0; ni < 4; ++ni) O[ni] *= fac;
    }
    float rs = 0.f;
#pragma unroll
    for (int ni = 0; ni < 4; ++ni)
#pragma unroll
      for (int r = 0; r < 4; ++r) {
        float pv = fexp2(S[ni][r] - m_);  // bounded by 2^8 under defer
        S[ni][r] = pv;
        rs += pv;
      }
    rs += __shfl_xor(rs, 16);
    rs += __shfl_xor(rs, 32);
    lsum += rs;

    // P^T -> per-wave LDS, packed b64
#pragma unroll
    for (int ni = 0; ni < 4; ++ni) {
      u16x4 pk;
#pragma unroll
      for (int r = 0; r < 4; ++r) pk[r] = f2bf(S[ni][r]);
      *(u16x4*)((char*)&Ps[w][0] + lr * 128 + ((ni * 32 + lg * 8) ^ xorv)) = pk;
    }
    bf16x8 pt[2];
#pragma unroll
    for (int ks = 0; ks < 2; ++ks)
      pt[ks] = *(const bf16x8*)((const char*)&Ps[w][0] + lr * 128 +
                                ((ks * 64 + lg * 16) ^ xorv));

    // O^T[ni] += mfma(V^T, P^T)
    __builtin_amdgcn_s_setprio(1);
#pragma unroll
    for (int ni = 0; ni < 4; ++ni) {
#pragma unroll
      for (int ks = 0; ks < 2; ++ks) {
        bf16x8 vf = *(const bf16x8*)(vbase + (ni * 16 + lr) * 128 +
                                     ((ks * 64 + lg * 16) ^ xorv));
        O[ni] = __builtin_amdgcn_mfma_f32_16x16x32_bf16(vf, pt[ks], O[ni], 0, 0, 0);
      }
    }
    __builtin_amdgcn_s_setprio(0);
    asm volatile("" ::: "memory");
    __builtin_amdgcn_s_barrier();
  }

  // epilogue: normalize + act_quant
  float rinv = 1.f / lsum;
  float o[4][4];
  float gm = 0.f;
#pragma unroll
  for (int ni = 0; ni < 4; ++ni)
#pragma unroll
    for (int r = 0; r < 4; ++r) {
      o[ni][r] = O[ni][r] * rinv;
      gm = fmaxf(gm, fabsf(o[ni][r]));
    }
  gm = fmaxf(gm, __shfl_xor(gm, 16));
  gm = fmaxf(gm, __shfl_xor(gm, 32));
  float gmc = fmaxf(gm, 1e-5f);
  float s = gmc * (1.f / 127.f);
  float inv = 127.f / gmc;
#pragma unroll
  for (int ni = 0; ni < 4; ++ni) {
    u16x4 ov;
#pragma unroll
    for (int r = 0; r < 4; ++r) {
      float q = fminf(fmaxf(rintf(o[ni][r] * inv), -127.f), 127.f) * s;
      ov[r] = f2bf(q);
    }
    *(u16x4*)(Y + (size_t)(qrow0 + lr) * 1024 + h * 64 + ni * 16 + lg * 4) = ov;
  }
}

// ---------------------------------------------------------------------------
extern "C" void kernel_launch(void* const* d_in, const int* in_sizes, int n_in,
                              void* d_out, int out_size, void* d_ws, size_t ws_size,
                              hipStream_t stream) {
  const float* x  = (const float*)d_in[0];
  const float* wq = (const float*)d_in[1];
  const float* wk = (const float*)d_in[2];
  const float* wv = (const float*)d_in[3];
  const float* wo = (const float*)d_in[4];
  const float* w1 = (const float*)d_in[5];
  const float* w2 = (const float*)d_in[6];
  const float* w3 = (const float*)d_in[7];
  const float* g1 = (const float*)d_in[8];
  const float* g2 = (const float*)d_in[9];

  char* ws = (char*)d_ws;
  const size_t MB = 1024 * 1024;
  u16* sgn   = (u16*)ws;
  u16* sWq   = (u16*)(ws + 0 * MB);
  u16* sWo   = (u16*)(ws + 6 * MB);
  u16* sW12  = (u16*)(ws + 8 * MB);    // interleaved [8192,1024]
  u16* sW3   = (u16*)(ws + 24 * MB);
  float* partial = (float*)(ws + 32 * MB);
  float* alphas  = (float*)(ws + 32 * MB + 16384);
  u16* Vt    = (u16*)(ws + 33 * MB);   // dead before x1 written
  float* x1  = (float*)(ws + 33 * MB); // fp32 [4096,1024]
  u16* hq    = (u16*)(ws + 49 * MB);   // bf16 [4096,1024]
  u16* qkv   = (u16*)(ws + 57 * MB);   // bf16 [4096,3072]
  u16* yb    = (u16*)(ws + 81 * MB);   // bf16 [4096,1024]
  u16* zq    = (u16*)(ws + 57 * MB);   // bf16 [4096,4096] (qkv,yb dead)

  // weight prep
  convert_sign_all<<<dim3(256, 7), 256, 0, stream>>>(wq, wk, wv, wo, w1, w2, w3,
                                                     sgn, partial);
  finalize_alpha<<<7, 256, 0, stream>>>(partial, alphas);

  // attention branch
  rmsnorm_quant<<<4096, 256, 0, stream>>>(x, g1, hq);
  gemm_bt<false, 128><<<dim3(24, 32), 256, 0, stream>>>(hq, sWq, alphas, 10, nullptr,
                                                        qkv, 4096, 3072, 1024);
  transpose_v<<<dim3(64, 16), 256, 0, stream>>>(qkv, Vt);
  attn_kernel<<<dim3(16, 64), 256, 0, stream>>>(qkv, Vt, yb);
  gemm_bt<true, 64><<<dim3(8, 64), 256, 0, stream>>>(yb, sWo, alphas + 3, 31, x,
                                                     x1, 4096, 1024, 1024);
  // FFN branch
  rmsnorm_quant<<<4096, 256, 0, stream>>>(x1, g2, hq);
  gemm_ffn<<<dim3(64, 32), 256, 0, stream>>>(hq, sW12, alphas + 4, zq);
  gemm_bt<true, 64><<<dim3(8, 64), 256, 0, stream>>>(zq, sW3, alphas + 6, 31, x1,
                                                     (float*)d_out, 4096, 1024, 4096);
}

// Round 9
// 331.798 us; speedup vs baseline: 1.0896x; 1.0222x over previous
//
#include <hip/hip_runtime.h>
#include <math.h>

// ============================================================================
// BitNet transformer block, MI355X (gfx950).  Round 9.
// R8 -> R9: gemm_ffn fine-grained interleave. W1/W2 interleaved at 16-row
// granularity (W12 row c16*32+u = W1 row c16*16+u for u<16, W2 for u>=16):
// each wave's ni=0/1 (and 2/3) fragments are y1/y2 of the SAME z-cols in the
// SAME lane -> silu in-register, NO 32KB f32 exchange (R8's 30us epilogue).
// Only cross-wave op: group-64 row-max via 1KB aliased staging LDS.
// ws layout (MB = 2^20):
//   0..32    sign weights (wq@0,wk@2,wv@4,wo@6, w12 interleaved@8..24, w3@24)
//   32..33   alpha partials (7*256 f32); alphas (7 f32) at +16KB
//   33..49   Vt bf16 [16][64][4096] (transpose->attn), then x1 fp32
//   49..57   hq bf16
//   57..89   qkv bf16 [4096,3072] (->attn), then zq bf16 [4096,4096]
//   81..89   yb bf16 (dead before zq written)
// ============================================================================

typedef unsigned short u16;
typedef __attribute__((ext_vector_type(4))) float f32x4;
typedef __attribute__((ext_vector_type(4))) unsigned short u16x4;
typedef __attribute__((ext_vector_type(8))) unsigned short u16x8;
typedef __attribute__((ext_vector_type(8))) __bf16 bf16x8;

#define DEV static __device__ __forceinline__

DEV float bf2f(u16 u) { union { unsigned i; float f; } c; c.i = ((unsigned)u) << 16; return c.f; }
DEV u16 f2bf(float f) { __bf16 b = (__bf16)f; return __builtin_bit_cast(u16, b); }
DEV float fexp2(float x) { float r; asm("v_exp_f32 %0, %1" : "=v"(r) : "v"(x)); return r; }

DEV void gload16(const void* g, void* l) {
  __builtin_amdgcn_global_load_lds((__attribute__((address_space(1))) void*)g,
                                   (__attribute__((address_space(3))) void*)l,
                                   16, 0, 0);
}

// ---------------------------------------------------------------------------
// Weight prep: sign(w) -> bf16 {+1,-1,0}, block-partial |w| sums.
// wi 4/5 (w1/w2) interleave at 16-row granularity into one buffer at +8MB.
// ---------------------------------------------------------------------------
__global__ __launch_bounds__(256) void convert_sign_all(
    const float* __restrict__ w0, const float* __restrict__ w1,
    const float* __restrict__ w2, const float* __restrict__ w3,
    const float* __restrict__ w4, const float* __restrict__ w5,
    const float* __restrict__ w6, u16* __restrict__ sgn_base,
    float* __restrict__ partial) {
  __shared__ float red[4];
  const int wi = blockIdx.y;
  const float* srcs[7] = {w0, w1, w2, w3, w4, w5, w6};
  const size_t offs[7] = {0, 1048576, 2097152, 3145728, 4194304, 4194304, 12582912};
  const float* w = srcs[wi];
  u16* sgn = sgn_base + offs[wi];
  const int n4 = (wi < 4) ? 262144 : 1048576;
  const bool ilv = (wi == 4) || (wi == 5);
  const int ilv_add = (wi == 5) ? 16 : 0;

  float s = 0.f;
  for (int i = blockIdx.x * 256 + threadIdx.x; i < n4; i += 256 * 256) {
    f32x4 v = ((const f32x4*)w)[i];
    u16x4 o;
#pragma unroll
    for (int j = 0; j < 4; ++j) {
      float f = v[j];
      o[j] = f > 0.f ? (u16)0x3F80 : (f < 0.f ? (u16)0xBF80 : (u16)0);
      s += fabsf(f);
    }
    size_t di = i;
    if (ilv) {
      int e = i << 2;                 // element index
      int row = e >> 10, col = e & 1023;
      int dst = ((row >> 4) << 5) + ilv_add + (row & 15);
      di = ((size_t)dst << 8) + (col >> 2);
    }
    ((u16x4*)sgn)[di] = o;
  }
#pragma unroll
  for (int off = 32; off >= 1; off >>= 1) s += __shfl_xor(s, off);
  if ((threadIdx.x & 63) == 0) red[threadIdx.x >> 6] = s;
  __syncthreads();
  if (threadIdx.x == 0)
    partial[wi * 256 + blockIdx.x] = red[0] + red[1] + red[2] + red[3];
}

__global__ __launch_bounds__(256) void finalize_alpha(
    const float* __restrict__ partial, float* __restrict__ alphas) {
  __shared__ float red[4];
  int wi = blockIdx.x;  // 0..6
  float v = partial[wi * 256 + threadIdx.x];
#pragma unroll
  for (int off = 32; off >= 1; off >>= 1) v += __shfl_xor(v, off);
  if ((threadIdx.x & 63) == 0) red[threadIdx.x >> 6] = v;
  __syncthreads();
  if (threadIdx.x == 0)
    alphas[wi] = (red[0] + red[1] + red[2] + red[3]) *
                 (wi < 4 ? (1.f / 1048576.f) : (1.f / 4194304.f));
}

// ---------------------------------------------------------------------------
// RMSNorm + act_quant (group 64). One block per row of 1024.
// ---------------------------------------------------------------------------
__global__ __launch_bounds__(256) void rmsnorm_quant(
    const float* __restrict__ x, const float* __restrict__ g, u16* __restrict__ out) {
  __shared__ float red[4];
  const int row = blockIdx.x, t = threadIdx.x;
  f32x4 v = ((const f32x4*)(x + (size_t)row * 1024))[t];
  float ss = v[0] * v[0] + v[1] * v[1] + v[2] * v[2] + v[3] * v[3];
#pragma unroll
  for (int off = 32; off >= 1; off >>= 1) ss += __shfl_xor(ss, off);
  if ((t & 63) == 0) red[t >> 6] = ss;
  __syncthreads();
  float tot = red[0] + red[1] + red[2] + red[3];
  float rinv = rsqrtf(tot * (1.f / 1024.f) + 1e-6f);
  f32x4 gg = ((const f32x4*)g)[t];
  float n[4];
#pragma unroll
  for (int j = 0; j < 4; ++j) n[j] = v[j] * rinv * gg[j];
  float gm = fmaxf(fmaxf(fabsf(n[0]), fabsf(n[1])), fmaxf(fabsf(n[2]), fabsf(n[3])));
#pragma unroll
  for (int off = 1; off <= 8; off <<= 1) gm = fmaxf(gm, __shfl_xor(gm, off));
  float s = fmaxf(gm, 1e-5f) / 127.0f;
  u16x4 o;
#pragma unroll
  for (int j = 0; j < 4; ++j) {
    float q = fminf(fmaxf(rintf(n[j] / s), -127.f), 127.f) * s;
    o[j] = f2bf(q);
  }
  ((u16x4*)out)[(size_t)row * 256 + t] = o;
}

// ---------------------------------------------------------------------------
// V transpose: qkv[:,2048+h*64 .. +63] -> Vt[h][d][t]  ([16][64][4096] bf16).
// ---------------------------------------------------------------------------
__global__ __launch_bounds__(256) void transpose_v(
    const u16* __restrict__ qkv, u16* __restrict__ Vt) {
  __shared__ u16 T[64][65];
  const int tt = blockIdx.x, h = blockIdx.y, tid = threadIdx.x;
#pragma unroll
  for (int i = 0; i < 2; ++i) {
    int idx = i * 2048 + tid * 8;
    int trow = idx >> 6, dcol = idx & 63;
    u16x8 v = *(const u16x8*)(qkv + (size_t)(tt * 64 + trow) * 3072 + 2048 + h * 64 + dcol);
#pragma unroll
    for (int j = 0; j < 8; ++j) T[dcol + j][trow] = v[j];
  }
  __syncthreads();
#pragma unroll
  for (int i = 0; i < 2; ++i) {
    int idx = i * 2048 + tid * 8;
    int drow = idx >> 6, tcol = idx & 63;
    u16x8 v;
#pragma unroll
    for (int j = 0; j < 8; ++j) v[j] = T[drow][tcol + j];
    *(u16x8*)(Vt + ((size_t)h * 64 + drow) * 4096 + tt * 64 + tcol) = v;
  }
}

// ---------------------------------------------------------------------------
// GEMM: C[M,N] = alpha[bcol>>ashift] * (A[M,K] @ B[N,K]^T) (+res).
// BMx128 tile, BK=64, 4 waves, global_load_lds w=16, XOR swizzle.
// ---------------------------------------------------------------------------
template <bool RES, int BM>
__global__ __launch_bounds__(256) void gemm_bt(
    const u16* __restrict__ A, const u16* __restrict__ B,
    const float* __restrict__ alpha, int ashift, const float* __restrict__ res,
    void* __restrict__ Cout, int M, int N, int K) {
  constexpr int NI = (BM == 128) ? 4 : 2;
  constexpr int WNE = (BM == 128) ? 64 : 32;
  __shared__ u16 As[BM * 64];
  __shared__ u16 Bs[128 * 64];
  const int tid = threadIdx.x;
  const int l = tid & 63, w = tid >> 6;
  const int wm = (BM == 128) ? (w >> 1) : 0;
  const int wn = (BM == 128) ? (w & 1) : w;
  const int lr = l & 15, lg = l >> 4;
  const int xorv = (l & 7) << 4;
  const int brow = blockIdx.y * BM;
  const int bcol = blockIdx.x * 128;
  const int src_chunk = (l & 7) ^ (l >> 3);
  const int rl = w * 8 + (l >> 3);

  f32x4 acc[4][NI];
#pragma unroll
  for (int i = 0; i < 4; ++i)
#pragma unroll
    for (int j = 0; j < NI; ++j) acc[i][j] = (f32x4){0.f, 0.f, 0.f, 0.f};

  const char* Ag = (const char*)A;
  const char* Bg = (const char*)B;
  const int nkt = K >> 6;
  for (int kt = 0; kt < nkt; ++kt) {
    __syncthreads();
    const size_t kb = (size_t)kt * 128 + src_chunk * 16;
#pragma unroll
    for (int it = 0; it < BM / 32; ++it)
      gload16(Ag + (size_t)(brow + it * 32 + rl) * (size_t)(K * 2) + kb,
              &As[(it * 32 + w * 8) * 64]);
#pragma unroll
    for (int it = 0; it < 4; ++it)
      gload16(Bg + (size_t)(bcol + it * 32 + rl) * (size_t)(K * 2) + kb,
              &Bs[(it * 32 + w * 8) * 64]);
    __syncthreads();

    bf16x8 af[4][2], bfr[NI][2];
#pragma unroll
    for (int mi = 0; mi < 4; ++mi)
#pragma unroll
      for (int ks = 0; ks < 2; ++ks) {
        int row = wm * 64 + mi * 16 + lr;
        af[mi][ks] = *(const bf16x8*)((const char*)As + row * 128 + ((ks * 64 + lg * 16) ^ xorv));
      }
#pragma unroll
    for (int ni = 0; ni < NI; ++ni)
#pragma unroll
      for (int ks = 0; ks < 2; ++ks) {
        int row = wn * WNE + ni * 16 + lr;
        bfr[ni][ks] = *(const bf16x8*)((const char*)Bs + row * 128 + ((ks * 64 + lg * 16) ^ xorv));
      }
#pragma unroll
    for (int ks = 0; ks < 2; ++ks)
#pragma unroll
      for (int mi = 0; mi < 4; ++mi)
#pragma unroll
        for (int ni = 0; ni < NI; ++ni)
          acc[mi][ni] = __builtin_amdgcn_mfma_f32_16x16x32_bf16(
              af[mi][ks], bfr[ni][ks], acc[mi][ni], 0, 0, 0);
  }

  const float scale = alpha[bcol >> ashift];
#pragma unroll
  for (int mi = 0; mi < 4; ++mi)
#pragma unroll
    for (int ni = 0; ni < NI; ++ni)
#pragma unroll
      for (int r = 0; r < 4; ++r) {
        int row = brow + wm * 64 + mi * 16 + lg * 4 + r;
        int col = bcol + wn * WNE + ni * 16 + lr;
        float vv = acc[mi][ni][r] * scale;
        if (RES)
          ((float*)Cout)[(size_t)row * N + col] = res[(size_t)row * N + col] + vv;
        else
          ((u16*)Cout)[(size_t)row * N + col] = f2bf(vv);
      }
}

// ---------------------------------------------------------------------------
// Fused FFN GEMM over fine-interleaved W12 [8192,1024]:
// W12 row c16*32+u = W1 row c16*16+u (u<16) | W2 row c16*16+u-16 (u>=16).
// Wave (wm,wn) tile rows: ni=0 -> y1 cols zc0+lr, ni=1 -> y2 same cols,
// ni=2/3 -> y1/y2 cols zc0+16+lr, where zc0 = bx*64 + wn*32.
// silu in-register; group-64 row-max via 1KB aliased staging LDS.
// ---------------------------------------------------------------------------
__global__ __launch_bounds__(256) void gemm_ffn(
    const u16* __restrict__ A, const u16* __restrict__ B12,
    const float* __restrict__ alpha2, u16* __restrict__ zq) {
  __shared__ u16 As[128 * 64];
  __shared__ u16 Bs[128 * 64];
  const int tid = threadIdx.x;
  const int l = tid & 63, w = tid >> 6;
  const int wm = w >> 1, wn = w & 1;
  const int lr = l & 15, lg = l >> 4;
  const int xorv = (l & 7) << 4;
  const int brow = blockIdx.y * 128;
  const int bcol = blockIdx.x * 128;  // W12 row block = 64 z-cols
  const int src_chunk = (l & 7) ^ (l >> 3);
  const int rl = w * 8 + (l >> 3);

  f32x4 acc[4][4];
#pragma unroll
  for (int i = 0; i < 4; ++i)
#pragma unroll
    for (int j = 0; j < 4; ++j) acc[i][j] = (f32x4){0.f, 0.f, 0.f, 0.f};

  for (int kt = 0; kt < 16; ++kt) {
    __syncthreads();
    const size_t kb = (size_t)kt * 128 + src_chunk * 16;
#pragma unroll
    for (int it = 0; it < 4; ++it) {
      gload16((const char*)A + (size_t)(brow + it * 32 + rl) * 2048 + kb,
              &As[(it * 32 + w * 8) * 64]);
      gload16((const char*)B12 + (size_t)(bcol + it * 32 + rl) * 2048 + kb,
              &Bs[(it * 32 + w * 8) * 64]);
    }
    __syncthreads();

    bf16x8 af[4][2], bfr[4][2];
#pragma unroll
    for (int mi = 0; mi < 4; ++mi)
#pragma unroll
      for (int ks = 0; ks < 2; ++ks) {
        int row = wm * 64 + mi * 16 + lr;
        af[mi][ks] = *(const bf16x8*)((const char*)As + row * 128 + ((ks * 64 + lg * 16) ^ xorv));
      }
#pragma unroll
    for (int ni = 0; ni < 4; ++ni)
#pragma unroll
      for (int ks = 0; ks < 2; ++ks) {
        int row = wn * 64 + ni * 16 + lr;
        bfr[ni][ks] = *(const bf16x8*)((const char*)Bs + row * 128 + ((ks * 64 + lg * 16) ^ xorv));
      }
#pragma unroll
    for (int ks = 0; ks < 2; ++ks)
#pragma unroll
      for (int mi = 0; mi < 4; ++mi)
#pragma unroll
        for (int ni = 0; ni < 4; ++ni)
          acc[mi][ni] = __builtin_amdgcn_mfma_f32_16x16x32_bf16(
              af[mi][ks], bfr[ni][ks], acc[mi][ni], 0, 0, 0);
  }

  // ---- epilogue: z = silu(a1*y1)*(a2*y2) in-register ----
  const float a1 = alpha2[0], a2 = alpha2[1];
  const float L2E = 1.4426950408889634f;
  float zl[4][4], zh[4][4], rm[4][4];
#pragma unroll
  for (int mi = 0; mi < 4; ++mi)
#pragma unroll
    for (int r = 0; r < 4; ++r) {
      float y1 = acc[mi][0][r] * a1;
      zl[mi][r] = y1 / (1.f + fexp2(-L2E * y1)) * (acc[mi][1][r] * a2);
      float y3 = acc[mi][2][r] * a1;
      zh[mi][r] = y3 / (1.f + fexp2(-L2E * y3)) * (acc[mi][3][r] * a2);
      float g = fmaxf(fabsf(zl[mi][r]), fabsf(zh[mi][r]));
#pragma unroll
      for (int off = 1; off <= 8; off <<= 1) g = fmaxf(g, __shfl_xor(g, off));
      rm[mi][r] = g;  // this wave's 32-col max for the row
    }

  // cross-wave (wn pair) row-max through aliased (dead) staging LDS
  float* rmax = (float*)&As[0];  // [4][64] f32 = 1KB
  __syncthreads();               // all waves done reading staging
  if (lr == 0) {
#pragma unroll
    for (int mi = 0; mi < 4; ++mi)
#pragma unroll
      for (int r = 0; r < 4; ++r)
        rmax[w * 64 + mi * 16 + lg * 4 + r] = rm[mi][r];
  }
  __syncthreads();

#pragma unroll
  for (int mi = 0; mi < 4; ++mi)
#pragma unroll
    for (int r = 0; r < 4; ++r) {
      float g = fmaxf(rm[mi][r], rmax[(w ^ 1) * 64 + mi * 16 + lg * 4 + r]);
      float gmc = fmaxf(g, 1e-5f);
      float s = gmc * (1.f / 127.f);
      float inv = 127.f / gmc;
      int row = brow + wm * 64 + mi * 16 + lg * 4 + r;
      int zc = blockIdx.x * 64 + wn * 32 + lr;
      float q0 = fminf(fmaxf(rintf(zl[mi][r] * inv), -127.f), 127.f) * s;
      float q1 = fminf(fmaxf(rintf(zh[mi][r] * inv), -127.f), 127.f) * s;
      zq[(size_t)row * 4096 + zc] = f2bf(q0);
      zq[(size_t)row * 4096 + zc + 16] = f2bf(q1);
    }
}

// ---------------------------------------------------------------------------
// Causal flash attention + act_quant epilogue.  SWAPPED-OPERAND form.
// Grid (16 heads, 64 q-tiles): qt = y<32 ? y : 95-y (balanced round-robin).
// Raw v_exp_f32 softmax, uniform-branched diag mask, setprio MFMA clusters.
// ---------------------------------------------------------------------------
__global__ __launch_bounds__(256) void attn_kernel(
    const u16* __restrict__ QKV, const u16* __restrict__ Vt, u16* __restrict__ Y) {
  __shared__ u16 Ks[2][64 * 64];  // [k-token 64][d 64] swizzled
  __shared__ u16 Vs[2][64 * 64];  // [d 64][k-token 64] swizzled
  __shared__ u16 Ps[4][16 * 64];  // per-wave P^T [q 16][token 64] swizzled

  const int tid = threadIdx.x;
  const int l = tid & 63, w = tid >> 6;
  const int lr = l & 15, lg = l >> 4;
  const int xorv = (l & 7) << 4;
  const int h = blockIdx.x;
  const int y = blockIdx.y;
  const int qt = (y < 32) ? y : (95 - y);
  const int src_chunk = (l & 7) ^ (l >> 3);
  const int rl = w * 8 + (l >> 3);
  const float SC = 0.18033688f;  // 0.125 * log2(e)

  const int qrow0 = qt * 64 + w * 16;
  const int nkt = qt + 1;

  bf16x8 qf[2];
#pragma unroll
  for (int ks = 0; ks < 2; ++ks)
    qf[ks] = __builtin_bit_cast(
        bf16x8, *(const u16x8*)(QKV + (size_t)(qrow0 + lr) * 3072 +
                                h * 64 + ks * 32 + lg * 8));

  f32x4 O[4];  // O^T: lane holds O[q=lr][d = ni*16 + lg*4 + r]
#pragma unroll
  for (int ni = 0; ni < 4; ++ni) O[ni] = (f32x4){0.f, 0.f, 0.f, 0.f};
  float m_ = -3e38f, lsum = 0.f;

  auto STAGE = [&](int buf, int kt) {
#pragma unroll
    for (int it = 0; it < 2; ++it) {
      int krow = kt * 64 + it * 32 + rl;
      gload16((const char*)QKV + ((size_t)krow * 3072 + 1024 + h * 64) * 2 + src_chunk * 16,
              &Ks[buf][(it * 32 + w * 8) * 64]);
      int drow = it * 32 + rl;
      gload16((const char*)Vt + (((size_t)h * 64 + drow) * 4096 + kt * 64) * 2 + src_chunk * 16,
              &Vs[buf][(it * 32 + w * 8) * 64]);
    }
  };

  STAGE(0, 0);
#pragma unroll 1
  for (int kt = 0; kt < nkt; ++kt) {
    const int cur = kt & 1;
    if (kt + 1 < nkt) {
      STAGE(cur ^ 1, kt + 1);
      asm volatile("s_waitcnt vmcnt(4)" ::: "memory");
    } else {
      asm volatile("s_waitcnt vmcnt(0)" ::: "memory");
    }
    __builtin_amdgcn_s_barrier();
    __builtin_amdgcn_sched_barrier(0);

    const char* kbase = (const char*)&Ks[cur][0];
    const char* vbase = (const char*)&Vs[cur][0];

    // S^T[ni] = mfma(K, Q)
    f32x4 S[4];
    __builtin_amdgcn_s_setprio(1);
#pragma unroll
    for (int ni = 0; ni < 4; ++ni) {
      S[ni] = (f32x4){0.f, 0.f, 0.f, 0.f};
#pragma unroll
      for (int ks = 0; ks < 2; ++ks) {
        bf16x8 kf = *(const bf16x8*)(kbase + (ni * 16 + lr) * 128 +
                                     ((ks * 64 + lg * 16) ^ xorv));
        S[ni] = __builtin_amdgcn_mfma_f32_16x16x32_bf16(kf, qf[ks], S[ni], 0, 0, 0);
      }
    }
    __builtin_amdgcn_s_setprio(0);

    // scale to exp2 domain; mask only on the (uniform) diagonal iteration
#pragma unroll
    for (int ni = 0; ni < 4; ++ni)
#pragma unroll
      for (int r = 0; r < 4; ++r) S[ni][r] *= SC;
    if (kt == qt) {
#pragma unroll
      for (int ni = 0; ni < 4; ++ni)
#pragma unroll
        for (int r = 0; r < 4; ++r)
          if ((ni * 16 + lg * 4 + r) > (w * 16 + lr)) S[ni][r] = -3e38f;
    }

    // online softmax (lane owns its q-row)
    float nm = -3e38f;
#pragma unroll
    for (int ni = 0; ni < 4; ++ni)
#pragma unroll
      for (int r = 0; r < 4; ++r) nm = fmaxf(nm, S[ni][r]);
    nm = fmaxf(nm, __shfl_xor(nm, 16));
    nm = fmaxf(nm, __shfl_xor(nm, 32));
    if (__ballot(nm > m_ + 8.f)) {  // T13 defer-rescale
      float mn = fmaxf(m_, nm);
      float fac = fexp2(m_ - mn);
      m_ = mn;
      lsum *= fac;
#pragma unroll
      for (int ni = 0; ni < 4; ++ni) O[ni] *= fac;
    }
    float rs = 0.f;
#pragma unroll
    for (int ni = 0; ni < 4; ++ni)
#pragma unroll
      for (int r = 0; r < 4; ++r) {
        float pv = fexp2(S[ni][r] - m_);  // bounded by 2^8 under defer
        S[ni][r] = pv;
        rs += pv;
      }
    rs += __shfl_xor(rs, 16);
    rs += __shfl_xor(rs, 32);
    lsum += rs;

    // P^T -> per-wave LDS, packed b64
#pragma unroll
    for (int ni = 0; ni < 4; ++ni) {
      u16x4 pk;
#pragma unroll
      for (int r = 0; r < 4; ++r) pk[r] = f2bf(S[ni][r]);
      *(u16x4*)((char*)&Ps[w][0] + lr * 128 + ((ni * 32 + lg * 8) ^ xorv)) = pk;
    }
    bf16x8 pt[2];
#pragma unroll
    for (int ks = 0; ks < 2; ++ks)
      pt[ks] = *(const bf16x8*)((const char*)&Ps[w][0] + lr * 128 +
                                ((ks * 64 + lg * 16) ^ xorv));

    // O^T[ni] += mfma(V^T, P^T)
    __builtin_amdgcn_s_setprio(1);
#pragma unroll
    for (int ni = 0; ni < 4; ++ni) {
#pragma unroll
      for (int ks = 0; ks < 2; ++ks) {
        bf16x8 vf = *(const bf16x8*)(vbase + (ni * 16 + lr) * 128 +
                                     ((ks * 64 + lg * 16) ^ xorv));
        O[ni] = __builtin_amdgcn_mfma_f32_16x16x32_bf16(vf, pt[ks], O[ni], 0, 0, 0);
      }
    }
    __builtin_amdgcn_s_setprio(0);
    asm volatile("" ::: "memory");
    __builtin_amdgcn_s_barrier();
  }

  // epilogue: normalize + act_quant
  float rinv = 1.f / lsum;
  float o[4][4];
  float gm = 0.f;
#pragma unroll
  for (int ni = 0; ni < 4; ++ni)
#pragma unroll
    for (int r = 0; r < 4; ++r) {
      o[ni][r] = O[ni][r] * rinv;
      gm = fmaxf(gm, fabsf(o[ni][r]));
    }
  gm = fmaxf(gm, __shfl_xor(gm, 16));
  gm = fmaxf(gm, __shfl_xor(gm, 32));
  float gmc = fmaxf(gm, 1e-5f);
  float s = gmc * (1.f / 127.f);
  float inv = 127.f / gmc;
#pragma unroll
  for (int ni = 0; ni < 4; ++ni) {
    u16x4 ov;
#pragma unroll
    for (int r = 0; r < 4; ++r) {
      float q = fminf(fmaxf(rintf(o[ni][r] * inv), -127.f), 127.f) * s;
      ov[r] = f2bf(q);
    }
    *(u16x4*)(Y + (size_t)(qrow0 + lr) * 1024 + h * 64 + ni * 16 + lg * 4) = ov;
  }
}

// ---------------------------------------------------------------------------
extern "C" void kernel_launch(void* const* d_in, const int* in_sizes, int n_in,
                              void* d_out, int out_size, void* d_ws, size_t ws_size,
                              hipStream_t stream) {
  const float* x  = (const float*)d_in[0];
  const float* wq = (const float*)d_in[1];
  const float* wk = (const float*)d_in[2];
  const float* wv = (const float*)d_in[3];
  const float* wo = (const float*)d_in[4];
  const float* w1 = (const float*)d_in[5];
  const float* w2 = (const float*)d_in[6];
  const float* w3 = (const float*)d_in[7];
  const float* g1 = (const float*)d_in[8];
  const float* g2 = (const float*)d_in[9];

  char* ws = (char*)d_ws;
  const size_t MB = 1024 * 1024;
  u16* sgn   = (u16*)ws;
  u16* sWq   = (u16*)(ws + 0 * MB);
  u16* sWo   = (u16*)(ws + 6 * MB);
  u16* sW12  = (u16*)(ws + 8 * MB);    // fine-interleaved [8192,1024]
  u16* sW3   = (u16*)(ws + 24 * MB);
  float* partial = (float*)(ws + 32 * MB);
  float* alphas  = (float*)(ws + 32 * MB + 16384);
  u16* Vt    = (u16*)(ws + 33 * MB);   // dead before x1 written
  float* x1  = (float*)(ws + 33 * MB); // fp32 [4096,1024]
  u16* hq    = (u16*)(ws + 49 * MB);   // bf16 [4096,1024]
  u16* qkv   = (u16*)(ws + 57 * MB);   // bf16 [4096,3072]
  u16* yb    = (u16*)(ws + 81 * MB);   // bf16 [4096,1024]
  u16* zq    = (u16*)(ws + 57 * MB);   // bf16 [4096,4096] (qkv,yb dead)

  // weight prep
  convert_sign_all<<<dim3(256, 7), 256, 0, stream>>>(wq, wk, wv, wo, w1, w2, w3,
                                                     sgn, partial);
  finalize_alpha<<<7, 256, 0, stream>>>(partial, alphas);

  // attention branch
  rmsnorm_quant<<<4096, 256, 0, stream>>>(x, g1, hq);
  gemm_bt<false, 128><<<dim3(24, 32), 256, 0, stream>>>(hq, sWq, alphas, 10, nullptr,
                                                        qkv, 4096, 3072, 1024);
  transpose_v<<<dim3(64, 16), 256, 0, stream>>>(qkv, Vt);
  attn_kernel<<<dim3(16, 64), 256, 0, stream>>>(qkv, Vt, yb);
  gemm_bt<true, 64><<<dim3(8, 64), 256, 0, stream>>>(yb, sWo, alphas + 3, 31, x,
                                                     x1, 4096, 1024, 1024);
  // FFN branch
  rmsnorm_quant<<<4096, 256, 0, stream>>>(x1, g2, hq);
  gemm_ffn<<<dim3(64, 32), 256, 0, stream>>>(hq, sW12, alphas + 4, zq);
  gemm_bt<true, 64><<<dim3(8, 64), 256, 0, stream>>>(zq, sW3, alphas + 6, 31, x1,
                                                     (float*)d_out, 4096, 1024, 4096);
}

// Round 10
// 309.583 us; speedup vs baseline: 1.1678x; 1.0718x over previous
//
#include <hip/hip_runtime.h>
#include <math.h>

// ============================================================================
// BitNet transformer block, MI355X (gfx950).  Round 10.
// R9 -> R10:
//  (a) gemm_ffn fat-wave: 256x128 tile, per-wave output 128x64 (was 64x64).
//      Diagnosis: 2-buffer GEMMs are LDS-BW-bound (16 b128 reads vs 32 MFMA
//      per wave-iter -> 21-27% MfmaUtil ceiling). Fat wave: 24 reads / 64
//      MFMA -> ~50% ceiling. LDS 48KB, acc 8x4, __launch_bounds__(256,2).
//  (b) rmsnorm#1 merged into convert_sign_all (blockIdx.y==7) - one less
//      serial dispatch, overlaps with BW-bound weight conversion.
// ws layout (MB = 2^20):
//   0..32    sign weights (wq@0,wk@2,wv@4,wo@6, w12 interleaved@8..24, w3@24)
//   32..33   alpha partials (7*256 f32); alphas (7 f32) at +16KB
//   33..49   Vt bf16 [16][64][4096] (transpose->attn), then x1 fp32
//   49..57   hq bf16
//   57..89   qkv bf16 [4096,3072] (->attn), then zq bf16 [4096,4096]
//   81..89   yb bf16 (dead before zq written)
// ============================================================================

typedef unsigned short u16;
typedef __attribute__((ext_vector_type(4))) float f32x4;
typedef __attribute__((ext_vector_type(4))) unsigned short u16x4;
typedef __attribute__((ext_vector_type(8))) unsigned short u16x8;
typedef __attribute__((ext_vector_type(8))) __bf16 bf16x8;

#define DEV static __device__ __forceinline__

DEV float bf2f(u16 u) { union { unsigned i; float f; } c; c.i = ((unsigned)u) << 16; return c.f; }
DEV u16 f2bf(float f) { __bf16 b = (__bf16)f; return __builtin_bit_cast(u16, b); }
DEV float fexp2(float x) { float r; asm("v_exp_f32 %0, %1" : "=v"(r) : "v"(x)); return r; }

DEV void gload16(const void* g, void* l) {
  __builtin_amdgcn_global_load_lds((__attribute__((address_space(1))) void*)g,
                                   (__attribute__((address_space(3))) void*)l,
                                   16, 0, 0);
}

// ---------------------------------------------------------------------------
// Weight prep: sign(w) -> bf16 {+1,-1,0}, block-partial |w| sums.
// wi 4/5 (w1/w2) interleave at 16-row granularity into one buffer at +8MB.
// wi==7: rmsnorm+act_quant of x (16 rows per block) - free overlap.
// ---------------------------------------------------------------------------
__global__ __launch_bounds__(256) void convert_sign_all(
    const float* __restrict__ w0, const float* __restrict__ w1,
    const float* __restrict__ w2, const float* __restrict__ w3,
    const float* __restrict__ w4, const float* __restrict__ w5,
    const float* __restrict__ w6, u16* __restrict__ sgn_base,
    float* __restrict__ partial,
    const float* __restrict__ x, const float* __restrict__ g1,
    u16* __restrict__ hq) {
  __shared__ float red[4];
  const int wi = blockIdx.y;
  const int t = threadIdx.x;

  if (wi == 7) {  // rmsnorm + act_quant for rows 16*bx .. +15
#pragma unroll 1
    for (int rr = 0; rr < 16; ++rr) {
      const int row = blockIdx.x * 16 + rr;
      f32x4 v = ((const f32x4*)(x + (size_t)row * 1024))[t];
      float ss = v[0] * v[0] + v[1] * v[1] + v[2] * v[2] + v[3] * v[3];
#pragma unroll
      for (int off = 32; off >= 1; off >>= 1) ss += __shfl_xor(ss, off);
      if ((t & 63) == 0) red[t >> 6] = ss;
      __syncthreads();
      float tot = red[0] + red[1] + red[2] + red[3];
      __syncthreads();
      float rinv = rsqrtf(tot * (1.f / 1024.f) + 1e-6f);
      f32x4 gg = ((const f32x4*)g1)[t];
      float n[4];
#pragma unroll
      for (int j = 0; j < 4; ++j) n[j] = v[j] * rinv * gg[j];
      float gm = fmaxf(fmaxf(fabsf(n[0]), fabsf(n[1])), fmaxf(fabsf(n[2]), fabsf(n[3])));
#pragma unroll
      for (int off = 1; off <= 8; off <<= 1) gm = fmaxf(gm, __shfl_xor(gm, off));
      float s = fmaxf(gm, 1e-5f) / 127.0f;
      u16x4 o;
#pragma unroll
      for (int j = 0; j < 4; ++j) {
        float q = fminf(fmaxf(rintf(n[j] / s), -127.f), 127.f) * s;
        o[j] = f2bf(q);
      }
      ((u16x4*)hq)[(size_t)row * 256 + t] = o;
    }
    return;
  }

  const float* srcs[7] = {w0, w1, w2, w3, w4, w5, w6};
  const size_t offs[7] = {0, 1048576, 2097152, 3145728, 4194304, 4194304, 12582912};
  const float* w = srcs[wi];
  u16* sgn = sgn_base + offs[wi];
  const int n4 = (wi < 4) ? 262144 : 1048576;
  const bool ilv = (wi == 4) || (wi == 5);
  const int ilv_add = (wi == 5) ? 16 : 0;

  float s = 0.f;
  for (int i = blockIdx.x * 256 + t; i < n4; i += 256 * 256) {
    f32x4 v = ((const f32x4*)w)[i];
    u16x4 o;
#pragma unroll
    for (int j = 0; j < 4; ++j) {
      float f = v[j];
      o[j] = f > 0.f ? (u16)0x3F80 : (f < 0.f ? (u16)0xBF80 : (u16)0);
      s += fabsf(f);
    }
    size_t di = i;
    if (ilv) {
      int e = i << 2;                 // element index
      int row = e >> 10, col = e & 1023;
      int dst = ((row >> 4) << 5) + ilv_add + (row & 15);
      di = ((size_t)dst << 8) + (col >> 2);
    }
    ((u16x4*)sgn)[di] = o;
  }
#pragma unroll
  for (int off = 32; off >= 1; off >>= 1) s += __shfl_xor(s, off);
  if ((t & 63) == 0) red[t >> 6] = s;
  __syncthreads();
  if (t == 0)
    partial[wi * 256 + blockIdx.x] = red[0] + red[1] + red[2] + red[3];
}

__global__ __launch_bounds__(256) void finalize_alpha(
    const float* __restrict__ partial, float* __restrict__ alphas) {
  __shared__ float red[4];
  int wi = blockIdx.x;  // 0..6
  float v = partial[wi * 256 + threadIdx.x];
#pragma unroll
  for (int off = 32; off >= 1; off >>= 1) v += __shfl_xor(v, off);
  if ((threadIdx.x & 63) == 0) red[threadIdx.x >> 6] = v;
  __syncthreads();
  if (threadIdx.x == 0)
    alphas[wi] = (red[0] + red[1] + red[2] + red[3]) *
                 (wi < 4 ? (1.f / 1048576.f) : (1.f / 4194304.f));
}

// ---------------------------------------------------------------------------
// RMSNorm + act_quant (group 64). One block per row of 1024.  (FFN branch)
// ---------------------------------------------------------------------------
__global__ __launch_bounds__(256) void rmsnorm_quant(
    const float* __restrict__ x, const float* __restrict__ g, u16* __restrict__ out) {
  __shared__ float red[4];
  const int row = blockIdx.x, t = threadIdx.x;
  f32x4 v = ((const f32x4*)(x + (size_t)row * 1024))[t];
  float ss = v[0] * v[0] + v[1] * v[1] + v[2] * v[2] + v[3] * v[3];
#pragma unroll
  for (int off = 32; off >= 1; off >>= 1) ss += __shfl_xor(ss, off);
  if ((t & 63) == 0) red[t >> 6] = ss;
  __syncthreads();
  float tot = red[0] + red[1] + red[2] + red[3];
  float rinv = rsqrtf(tot * (1.f / 1024.f) + 1e-6f);
  f32x4 gg = ((const f32x4*)g)[t];
  float n[4];
#pragma unroll
  for (int j = 0; j < 4; ++j) n[j] = v[j] * rinv * gg[j];
  float gm = fmaxf(fmaxf(fabsf(n[0]), fabsf(n[1])), fmaxf(fabsf(n[2]), fabsf(n[3])));
#pragma unroll
  for (int off = 1; off <= 8; off <<= 1) gm = fmaxf(gm, __shfl_xor(gm, off));
  float s = fmaxf(gm, 1e-5f) / 127.0f;
  u16x4 o;
#pragma unroll
  for (int j = 0; j < 4; ++j) {
    float q = fminf(fmaxf(rintf(n[j] / s), -127.f), 127.f) * s;
    o[j] = f2bf(q);
  }
  ((u16x4*)out)[(size_t)row * 256 + t] = o;
}

// ---------------------------------------------------------------------------
// V transpose: qkv[:,2048+h*64 .. +63] -> Vt[h][d][t]  ([16][64][4096] bf16).
// ---------------------------------------------------------------------------
__global__ __launch_bounds__(256) void transpose_v(
    const u16* __restrict__ qkv, u16* __restrict__ Vt) {
  __shared__ u16 T[64][65];
  const int tt = blockIdx.x, h = blockIdx.y, tid = threadIdx.x;
#pragma unroll
  for (int i = 0; i < 2; ++i) {
    int idx = i * 2048 + tid * 8;
    int trow = idx >> 6, dcol = idx & 63;
    u16x8 v = *(const u16x8*)(qkv + (size_t)(tt * 64 + trow) * 3072 + 2048 + h * 64 + dcol);
#pragma unroll
    for (int j = 0; j < 8; ++j) T[dcol + j][trow] = v[j];
  }
  __syncthreads();
#pragma unroll
  for (int i = 0; i < 2; ++i) {
    int idx = i * 2048 + tid * 8;
    int drow = idx >> 6, tcol = idx & 63;
    u16x8 v;
#pragma unroll
    for (int j = 0; j < 8; ++j) v[j] = T[drow][tcol + j];
    *(u16x8*)(Vt + ((size_t)h * 64 + drow) * 4096 + tt * 64 + tcol) = v;
  }
}

// ---------------------------------------------------------------------------
// GEMM: C[M,N] = alpha[bcol>>ashift] * (A[M,K] @ B[N,K]^T) (+res).
// BMx128 tile, BK=64, 4 waves, global_load_lds w=16, XOR swizzle.
// ---------------------------------------------------------------------------
template <bool RES, int BM>
__global__ __launch_bounds__(256) void gemm_bt(
    const u16* __restrict__ A, const u16* __restrict__ B,
    const float* __restrict__ alpha, int ashift, const float* __restrict__ res,
    void* __restrict__ Cout, int M, int N, int K) {
  constexpr int NI = (BM == 128) ? 4 : 2;
  constexpr int WNE = (BM == 128) ? 64 : 32;
  __shared__ u16 As[BM * 64];
  __shared__ u16 Bs[128 * 64];
  const int tid = threadIdx.x;
  const int l = tid & 63, w = tid >> 6;
  const int wm = (BM == 128) ? (w >> 1) : 0;
  const int wn = (BM == 128) ? (w & 1) : w;
  const int lr = l & 15, lg = l >> 4;
  const int xorv = (l & 7) << 4;
  const int brow = blockIdx.y * BM;
  const int bcol = blockIdx.x * 128;
  const int src_chunk = (l & 7) ^ (l >> 3);
  const int rl = w * 8 + (l >> 3);

  f32x4 acc[4][NI];
#pragma unroll
  for (int i = 0; i < 4; ++i)
#pragma unroll
    for (int j = 0; j < NI; ++j) acc[i][j] = (f32x4){0.f, 0.f, 0.f, 0.f};

  const char* Ag = (const char*)A;
  const char* Bg = (const char*)B;
  const int nkt = K >> 6;
  for (int kt = 0; kt < nkt; ++kt) {
    __syncthreads();
    const size_t kb = (size_t)kt * 128 + src_chunk * 16;
#pragma unroll
    for (int it = 0; it < BM / 32; ++it)
      gload16(Ag + (size_t)(brow + it * 32 + rl) * (size_t)(K * 2) + kb,
              &As[(it * 32 + w * 8) * 64]);
#pragma unroll
    for (int it = 0; it < 4; ++it)
      gload16(Bg + (size_t)(bcol + it * 32 + rl) * (size_t)(K * 2) + kb,
              &Bs[(it * 32 + w * 8) * 64]);
    __syncthreads();

    bf16x8 af[4][2], bfr[NI][2];
#pragma unroll
    for (int mi = 0; mi < 4; ++mi)
#pragma unroll
      for (int ks = 0; ks < 2; ++ks) {
        int row = wm * 64 + mi * 16 + lr;
        af[mi][ks] = *(const bf16x8*)((const char*)As + row * 128 + ((ks * 64 + lg * 16) ^ xorv));
      }
#pragma unroll
    for (int ni = 0; ni < NI; ++ni)
#pragma unroll
      for (int ks = 0; ks < 2; ++ks) {
        int row = wn * WNE + ni * 16 + lr;
        bfr[ni][ks] = *(const bf16x8*)((const char*)Bs + row * 128 + ((ks * 64 + lg * 16) ^ xorv));
      }
#pragma unroll
    for (int ks = 0; ks < 2; ++ks)
#pragma unroll
      for (int mi = 0; mi < 4; ++mi)
#pragma unroll
        for (int ni = 0; ni < NI; ++ni)
          acc[mi][ni] = __builtin_amdgcn_mfma_f32_16x16x32_bf16(
              af[mi][ks], bfr[ni][ks], acc[mi][ni], 0, 0, 0);
  }

  const float scale = alpha[bcol >> ashift];
#pragma unroll
  for (int mi = 0; mi < 4; ++mi)
#pragma unroll
    for (int ni = 0; ni < NI; ++ni)
#pragma unroll
      for (int r = 0; r < 4; ++r) {
        int row = brow + wm * 64 + mi * 16 + lg * 4 + r;
        int col = bcol + wn * WNE + ni * 16 + lr;
        float vv = acc[mi][ni][r] * scale;
        if (RES)
          ((float*)Cout)[(size_t)row * N + col] = res[(size_t)row * N + col] + vv;
        else
          ((u16*)Cout)[(size_t)row * N + col] = f2bf(vv);
      }
}

// ---------------------------------------------------------------------------
// Fused FFN GEMM, fat-wave: tile 256(M) x 128(W12 rows = 64 z-cols),
// 4 waves, per-wave output 128x64 (acc 8x4). W12 fine-interleaved (16-row):
// wave fragments ni=0/2 -> y1, ni=1/3 -> y2 of the same z-cols in-lane.
// 24 LDS reads / 64 MFMA per wave-iter (was 16/32) -> ~2x MFMA per LDS byte.
// ---------------------------------------------------------------------------
__global__ __launch_bounds__(256, 2) void gemm_ffn(
    const u16* __restrict__ A, const u16* __restrict__ B12,
    const float* __restrict__ alpha2, u16* __restrict__ zq) {
  __shared__ u16 As[256 * 64];  // 32KB
  __shared__ u16 Bs[128 * 64];  // 16KB
  const int tid = threadIdx.x;
  const int l = tid & 63, w = tid >> 6;
  const int wm = w >> 1, wn = w & 1;
  const int lr = l & 15, lg = l >> 4;
  const int xorv = (l & 7) << 4;
  const int brow = blockIdx.y * 256;
  const int bcol = blockIdx.x * 128;  // W12 row block = 64 z-cols
  const int src_chunk = (l & 7) ^ (l >> 3);
  const int rl = w * 8 + (l >> 3);

  f32x4 acc[8][4];
#pragma unroll
  for (int i = 0; i < 8; ++i)
#pragma unroll
    for (int j = 0; j < 4; ++j) acc[i][j] = (f32x4){0.f, 0.f, 0.f, 0.f};

  for (int kt = 0; kt < 16; ++kt) {
    __syncthreads();
    const size_t kb = (size_t)kt * 128 + src_chunk * 16;
#pragma unroll
    for (int it = 0; it < 8; ++it)
      gload16((const char*)A + (size_t)(brow + it * 32 + rl) * 2048 + kb,
              &As[(it * 32 + w * 8) * 64]);
#pragma unroll
    for (int it = 0; it < 4; ++it)
      gload16((const char*)B12 + (size_t)(bcol + it * 32 + rl) * 2048 + kb,
              &Bs[(it * 32 + w * 8) * 64]);
    __syncthreads();

#pragma unroll
    for (int ks = 0; ks < 2; ++ks) {
      bf16x8 bfr[4];
#pragma unroll
      for (int ni = 0; ni < 4; ++ni)
        bfr[ni] = *(const bf16x8*)((const char*)Bs + (wn * 64 + ni * 16 + lr) * 128 +
                                   ((ks * 64 + lg * 16) ^ xorv));
#pragma unroll
      for (int mi = 0; mi < 8; ++mi) {
        bf16x8 af = *(const bf16x8*)((const char*)As + (wm * 128 + mi * 16 + lr) * 128 +
                                     ((ks * 64 + lg * 16) ^ xorv));
#pragma unroll
        for (int ni = 0; ni < 4; ++ni)
          acc[mi][ni] = __builtin_amdgcn_mfma_f32_16x16x32_bf16(
              af, bfr[ni], acc[mi][ni], 0, 0, 0);
      }
    }
  }

  // ---- epilogue: z = silu(a1*y1)*(a2*y2) in-register ----
  const float a1 = alpha2[0], a2 = alpha2[1];
  const float L2E = 1.4426950408889634f;
  float zl[8][4], zh[8][4], rm[8][4];
#pragma unroll
  for (int mi = 0; mi < 8; ++mi)
#pragma unroll
    for (int r = 0; r < 4; ++r) {
      float y1 = acc[mi][0][r] * a1;
      zl[mi][r] = y1 / (1.f + fexp2(-L2E * y1)) * (acc[mi][1][r] * a2);
      float y3 = acc[mi][2][r] * a1;
      zh[mi][r] = y3 / (1.f + fexp2(-L2E * y3)) * (acc[mi][3][r] * a2);
      float g = fmaxf(fabsf(zl[mi][r]), fabsf(zh[mi][r]));
#pragma unroll
      for (int off = 1; off <= 8; off <<= 1) g = fmaxf(g, __shfl_xor(g, off));
      rm[mi][r] = g;  // this wave's 32-col max for the row
    }

  // cross-wave (wn pair: w and w^1 share wm) row-max via aliased staging LDS
  float* rmax = (float*)&As[0];  // [4][128] f32 = 2KB
  __syncthreads();               // all waves done reading staging
  if (lr == 0) {
#pragma unroll
    for (int mi = 0; mi < 8; ++mi)
#pragma unroll
      for (int r = 0; r < 4; ++r)
        rmax[w * 128 + mi * 16 + lg * 4 + r] = rm[mi][r];
  }
  __syncthreads();

#pragma unroll
  for (int mi = 0; mi < 8; ++mi)
#pragma unroll
    for (int r = 0; r < 4; ++r) {
      float g = fmaxf(rm[mi][r], rmax[(w ^ 1) * 128 + mi * 16 + lg * 4 + r]);
      float gmc = fmaxf(g, 1e-5f);
      float s = gmc * (1.f / 127.f);
      float inv = 127.f / gmc;
      int row = brow + wm * 128 + mi * 16 + lg * 4 + r;
      int zc = blockIdx.x * 64 + wn * 32 + lr;
      float q0 = fminf(fmaxf(rintf(zl[mi][r] * inv), -127.f), 127.f) * s;
      float q1 = fminf(fmaxf(rintf(zh[mi][r] * inv), -127.f), 127.f) * s;
      zq[(size_t)row * 4096 + zc] = f2bf(q0);
      zq[(size_t)row * 4096 + zc + 16] = f2bf(q1);
    }
}

// ---------------------------------------------------------------------------
// Causal flash attention + act_quant epilogue.  SWAPPED-OPERAND form.
// Grid (16 heads, 64 q-tiles): qt = y<32 ? y : 95-y (balanced round-robin).
// Raw v_exp_f32 softmax, uniform-branched diag mask, setprio MFMA clusters.
// ---------------------------------------------------------------------------
__global__ __launch_bounds__(256) void attn_kernel(
    const u16* __restrict__ QKV, const u16* __restrict__ Vt, u16* __restrict__ Y) {
  __shared__ u16 Ks[2][64 * 64];  // [k-token 64][d 64] swizzled
  __shared__ u16 Vs[2][64 * 64];  // [d 64][k-token 64] swizzled
  __shared__ u16 Ps[4][16 * 64];  // per-wave P^T [q 16][token 64] swizzled

  const int tid = threadIdx.x;
  const int l = tid & 63, w = tid >> 6;
  const int lr = l & 15, lg = l >> 4;
  const int xorv = (l & 7) << 4;
  const int h = blockIdx.x;
  const int y = blockIdx.y;
  const int qt = (y < 32) ? y : (95 - y);
  const int src_chunk = (l & 7) ^ (l >> 3);
  const int rl = w * 8 + (l >> 3);
  const float SC = 0.18033688f;  // 0.125 * log2(e)

  const int qrow0 = qt * 64 + w * 16;
  const int nkt = qt + 1;

  bf16x8 qf[2];
#pragma unroll
  for (int ks = 0; ks < 2; ++ks)
    qf[ks] = __builtin_bit_cast(
        bf16x8, *(const u16x8*)(QKV + (size_t)(qrow0 + lr) * 3072 +
                                h * 64 + ks * 32 + lg * 8));

  f32x4 O[4];  // O^T: lane holds O[q=lr][d = ni*16 + lg*4 + r]
#pragma unroll
  for (int ni = 0; ni < 4; ++ni) O[ni] = (f32x4){0.f, 0.f, 0.f, 0.f};
  float m_ = -3e38f, lsum = 0.f;

  auto STAGE = [&](int buf, int kt) {
#pragma unroll
    for (int it = 0; it < 2; ++it) {
      int krow = kt * 64 + it * 32 + rl;
      gload16((const char*)QKV + ((size_t)krow * 3072 + 1024 + h * 64) * 2 + src_chunk * 16,
              &Ks[buf][(it * 32 + w * 8) * 64]);
      int drow = it * 32 + rl;
      gload16((const char*)Vt + (((size_t)h * 64 + drow) * 4096 + kt * 64) * 2 + src_chunk * 16,
              &Vs[buf][(it * 32 + w * 8) * 64]);
    }
  };

  STAGE(0, 0);
#pragma unroll 1
  for (int kt = 0; kt < nkt; ++kt) {
    const int cur = kt & 1;
    if (kt + 1 < nkt) {
      STAGE(cur ^ 1, kt + 1);
      asm volatile("s_waitcnt vmcnt(4)" ::: "memory");
    } else {
      asm volatile("s_waitcnt vmcnt(0)" ::: "memory");
    }
    __builtin_amdgcn_s_barrier();
    __builtin_amdgcn_sched_barrier(0);

    const char* kbase = (const char*)&Ks[cur][0];
    const char* vbase = (const char*)&Vs[cur][0];

    // S^T[ni] = mfma(K, Q)
    f32x4 S[4];
    __builtin_amdgcn_s_setprio(1);
#pragma unroll
    for (int ni = 0; ni < 4; ++ni) {
      S[ni] = (f32x4){0.f, 0.f, 0.f, 0.f};
#pragma unroll
      for (int ks = 0; ks < 2; ++ks) {
        bf16x8 kf = *(const bf16x8*)(kbase + (ni * 16 + lr) * 128 +
                                     ((ks * 64 + lg * 16) ^ xorv));
        S[ni] = __builtin_amdgcn_mfma_f32_16x16x32_bf16(kf, qf[ks], S[ni], 0, 0, 0);
      }
    }
    __builtin_amdgcn_s_setprio(0);

    // scale to exp2 domain; mask only on the (uniform) diagonal iteration
#pragma unroll
    for (int ni = 0; ni < 4; ++ni)
#pragma unroll
      for (int r = 0; r < 4; ++r) S[ni][r] *= SC;
    if (kt == qt) {
#pragma unroll
      for (int ni = 0; ni < 4; ++ni)
#pragma unroll
        for (int r = 0; r < 4; ++r)
          if ((ni * 16 + lg * 4 + r) > (w * 16 + lr)) S[ni][r] = -3e38f;
    }

    // online softmax (lane owns its q-row)
    float nm = -3e38f;
#pragma unroll
    for (int ni = 0; ni < 4; ++ni)
#pragma unroll
      for (int r = 0; r < 4; ++r) nm = fmaxf(nm, S[ni][r]);
    nm = fmaxf(nm, __shfl_xor(nm, 16));
    nm = fmaxf(nm, __shfl_xor(nm, 32));
    if (__ballot(nm > m_ + 8.f)) {  // T13 defer-rescale
      float mn = fmaxf(m_, nm);
      float fac = fexp2(m_ - mn);
      m_ = mn;
      lsum *= fac;
#pragma unroll
      for (int ni = 0; ni < 4; ++ni) O[ni] *= fac;
    }
    float rs = 0.f;
#pragma unroll
    for (int ni = 0; ni < 4; ++ni)
#pragma unroll
      for (int r = 0; r < 4; ++r) {
        float pv = fexp2(S[ni][r] - m_);  // bounded by 2^8 under defer
        S[ni][r] = pv;
        rs += pv;
      }
    rs += __shfl_xor(rs, 16);
    rs += __shfl_xor(rs, 32);
    lsum += rs;

    // P^T -> per-wave LDS, packed b64
#pragma unroll
    for (int ni = 0; ni < 4; ++ni) {
      u16x4 pk;
#pragma unroll
      for (int r = 0; r < 4; ++r) pk[r] = f2bf(S[ni][r]);
      *(u16x4*)((char*)&Ps[w][0] + lr * 128 + ((ni * 32 + lg * 8) ^ xorv)) = pk;
    }
    bf16x8 pt[2];
#pragma unroll
    for (int ks = 0; ks < 2; ++ks)
      pt[ks] = *(const bf16x8*)((const char*)&Ps[w][0] + lr * 128 +
                                ((ks * 64 + lg * 16) ^ xorv));

    // O^T[ni] += mfma(V^T, P^T)
    __builtin_amdgcn_s_setprio(1);
#pragma unroll
    for (int ni = 0; ni < 4; ++ni) {
#pragma unroll
      for (int ks = 0; ks < 2; ++ks) {
        bf16x8 vf = *(const bf16x8*)(vbase + (ni * 16 + lr) * 128 +
                                     ((ks * 64 + lg * 16) ^ xorv));
        O[ni] = __builtin_amdgcn_mfma_f32_16x16x32_bf16(vf, pt[ks], O[ni], 0, 0, 0);
      }
    }
    __builtin_amdgcn_s_setprio(0);
    asm volatile("" ::: "memory");
    __builtin_amdgcn_s_barrier();
  }

  // epilogue: normalize + act_quant
  float rinv = 1.f / lsum;
  float o[4][4];
  float gm = 0.f;
#pragma unroll
  for (int ni = 0; ni < 4; ++ni)
#pragma unroll
    for (int r = 0; r < 4; ++r) {
      o[ni][r] = O[ni][r] * rinv;
      gm = fmaxf(gm, fabsf(o[ni][r]));
    }
  gm = fmaxf(gm, __shfl_xor(gm, 16));
  gm = fmaxf(gm, __shfl_xor(gm, 32));
  float gmc = fmaxf(gm, 1e-5f);
  float s = gmc * (1.f / 127.f);
  float inv = 127.f / gmc;
#pragma unroll
  for (int ni = 0; ni < 4; ++ni) {
    u16x4 ov;
#pragma unroll
    for (int r = 0; r < 4; ++r) {
      float q = fminf(fmaxf(rintf(o[ni][r] * inv), -127.f), 127.f) * s;
      ov[r] = f2bf(q);
    }
    *(u16x4*)(Y + (size_t)(qrow0 + lr) * 1024 + h * 64 + ni * 16 + lg * 4) = ov;
  }
}

// ---------------------------------------------------------------------------
extern "C" void kernel_launch(void* const* d_in, const int* in_sizes, int n_in,
                              void* d_out, int out_size, void* d_ws, size_t ws_size,
                              hipStream_t stream) {
  const float* x  = (const float*)d_in[0];
  const float* wq = (const float*)d_in[1];
  const float* wk = (const float*)d_in[2];
  const float* wv = (const float*)d_in[3];
  const float* wo = (const float*)d_in[4];
  const float* w1 = (const float*)d_in[5];
  const float* w2 = (const float*)d_in[6];
  const float* w3 = (const float*)d_in[7];
  const float* g1 = (const float*)d_in[8];
  const float* g2 = (const float*)d_in[9];

  char* ws = (char*)d_ws;
  const size_t MB = 1024 * 1024;
  u16* sgn   = (u16*)ws;
  u16* sWq   = (u16*)(ws + 0 * MB);
  u16* sWo   = (u16*)(ws + 6 * MB);
  u16* sW12  = (u16*)(ws + 8 * MB);    // fine-interleaved [8192,1024]
  u16* sW3   = (u16*)(ws + 24 * MB);
  float* partial = (float*)(ws + 32 * MB);
  float* alphas  = (float*)(ws + 32 * MB + 16384);
  u16* Vt    = (u16*)(ws + 33 * MB);   // dead before x1 written
  float* x1  = (float*)(ws + 33 * MB); // fp32 [4096,1024]
  u16* hq    = (u16*)(ws + 49 * MB);   // bf16 [4096,1024]
  u16* qkv   = (u16*)(ws + 57 * MB);   // bf16 [4096,3072]
  u16* yb    = (u16*)(ws + 81 * MB);   // bf16 [4096,1024]
  u16* zq    = (u16*)(ws + 57 * MB);   // bf16 [4096,4096] (qkv,yb dead)

  // weight prep + rmsnorm#1 (y==7) fused
  convert_sign_all<<<dim3(256, 8), 256, 0, stream>>>(wq, wk, wv, wo, w1, w2, w3,
                                                     sgn, partial, x, g1, hq);
  finalize_alpha<<<7, 256, 0, stream>>>(partial, alphas);

  // attention branch
  gemm_bt<false, 128><<<dim3(24, 32), 256, 0, stream>>>(hq, sWq, alphas, 10, nullptr,
                                                        qkv, 4096, 3072, 1024);
  transpose_v<<<dim3(64, 16), 256, 0, stream>>>(qkv, Vt);
  attn_kernel<<<dim3(16, 64), 256, 0, stream>>>(qkv, Vt, yb);
  gemm_bt<true, 64><<<dim3(8, 64), 256, 0, stream>>>(yb, sWo, alphas + 3, 31, x,
                                                     x1, 4096, 1024, 1024);
  // FFN branch
  rmsnorm_quant<<<4096, 256, 0, stream>>>(x1, g2, hq);
  gemm_ffn<<<dim3(64, 16), 256, 0, stream>>>(hq, sW12, alphas + 4, zq);
  gemm_bt<true, 64><<<dim3(8, 64), 256, 0, stream>>>(zq, sW3, alphas + 6, 31, x1,
                                                     (float*)d_out, 4096, 1024, 4096);
}

// Round 11
// 307.426 us; speedup vs baseline: 1.1760x; 1.0070x over previous
//
#include <hip/hip_runtime.h>
#include <math.h>

// ============================================================================
// BitNet transformer block, MI355X (gfx950).  Round 11.
// R10 -> R11:
//  (a) attn: 8-wave blocks (512 thr), QBLK=128: one staged 64-tok K/V tile
//      serves 8 waves (was 4) -> per-CU iteration slots 130 -> 66. Balanced:
//      grid (16,32), qt = y<16?y:47-y -> every CU exactly 66 k-iters.
//      VALU diet v2: exp2(fma(S,SC,-m)) fold (max on raw S), cvt_pk bf16
//      packing for P^T. ~45% fewer VALU ops/iter.
//  (b) qkv GEMM -> gemm_fat (gemm_ffn's 256x128 fat-wave loop + plain
//      alpha/bf16 epilogue), grid (24,16).
// ws layout (MB = 2^20):
//   0..32    sign weights (wq@0,wk@2,wv@4,wo@6, w12 interleaved@8..24, w3@24)
//   32..33   alpha partials (7*256 f32); alphas (7 f32) at +16KB
//   33..49   Vt bf16 [16][64][4096] (transpose->attn), then x1 fp32
//   49..57   hq bf16
//   57..89   qkv bf16 [4096,3072] (->attn), then zq bf16 [4096,4096]
//   81..89   yb bf16 (dead before zq written)
// ============================================================================

typedef unsigned short u16;
typedef unsigned int u32;
typedef __attribute__((ext_vector_type(2))) unsigned int u32x2;
typedef __attribute__((ext_vector_type(4))) float f32x4;
typedef __attribute__((ext_vector_type(4))) unsigned short u16x4;
typedef __attribute__((ext_vector_type(8))) unsigned short u16x8;
typedef __attribute__((ext_vector_type(8))) __bf16 bf16x8;

#define DEV static __device__ __forceinline__

DEV float bf2f(u16 u) { union { unsigned i; float f; } c; c.i = ((unsigned)u) << 16; return c.f; }
DEV u16 f2bf(float f) { __bf16 b = (__bf16)f; return __builtin_bit_cast(u16, b); }
DEV float fexp2(float x) { float r; asm("v_exp_f32 %0, %1" : "=v"(r) : "v"(x)); return r; }
DEV u32 cvtpk(float lo, float hi) {
  u32 r; asm("v_cvt_pk_bf16_f32 %0, %1, %2" : "=v"(r) : "v"(lo), "v"(hi)); return r;
}

DEV void gload16(const void* g, void* l) {
  __builtin_amdgcn_global_load_lds((__attribute__((address_space(1))) void*)g,
                                   (__attribute__((address_space(3))) void*)l,
                                   16, 0, 0);
}

// ---------------------------------------------------------------------------
// Weight prep: sign(w) -> bf16 {+1,-1,0}, block-partial |w| sums.
// wi 4/5 (w1/w2) interleave at 16-row granularity into one buffer at +8MB.
// wi==7: rmsnorm+act_quant of x (16 rows per block) - free overlap.
// ---------------------------------------------------------------------------
__global__ __launch_bounds__(256) void convert_sign_all(
    const float* __restrict__ w0, const float* __restrict__ w1,
    const float* __restrict__ w2, const float* __restrict__ w3,
    const float* __restrict__ w4, const float* __restrict__ w5,
    const float* __restrict__ w6, u16* __restrict__ sgn_base,
    float* __restrict__ partial,
    const float* __restrict__ x, const float* __restrict__ g1,
    u16* __restrict__ hq) {
  __shared__ float red[4];
  const int wi = blockIdx.y;
  const int t = threadIdx.x;

  if (wi == 7) {  // rmsnorm + act_quant for rows 16*bx .. +15
#pragma unroll 1
    for (int rr = 0; rr < 16; ++rr) {
      const int row = blockIdx.x * 16 + rr;
      f32x4 v = ((const f32x4*)(x + (size_t)row * 1024))[t];
      float ss = v[0] * v[0] + v[1] * v[1] + v[2] * v[2] + v[3] * v[3];
#pragma unroll
      for (int off = 32; off >= 1; off >>= 1) ss += __shfl_xor(ss, off);
      if ((t & 63) == 0) red[t >> 6] = ss;
      __syncthreads();
      float tot = red[0] + red[1] + red[2] + red[3];
      __syncthreads();
      float rinv = rsqrtf(tot * (1.f / 1024.f) + 1e-6f);
      f32x4 gg = ((const f32x4*)g1)[t];
      float n[4];
#pragma unroll
      for (int j = 0; j < 4; ++j) n[j] = v[j] * rinv * gg[j];
      float gm = fmaxf(fmaxf(fabsf(n[0]), fabsf(n[1])), fmaxf(fabsf(n[2]), fabsf(n[3])));
#pragma unroll
      for (int off = 1; off <= 8; off <<= 1) gm = fmaxf(gm, __shfl_xor(gm, off));
      float s = fmaxf(gm, 1e-5f) / 127.0f;
      u16x4 o;
#pragma unroll
      for (int j = 0; j < 4; ++j) {
        float q = fminf(fmaxf(rintf(n[j] / s), -127.f), 127.f) * s;
        o[j] = f2bf(q);
      }
      ((u16x4*)hq)[(size_t)row * 256 + t] = o;
    }
    return;
  }

  const float* srcs[7] = {w0, w1, w2, w3, w4, w5, w6};
  const size_t offs[7] = {0, 1048576, 2097152, 3145728, 4194304, 4194304, 12582912};
  const float* w = srcs[wi];
  u16* sgn = sgn_base + offs[wi];
  const int n4 = (wi < 4) ? 262144 : 1048576;
  const bool ilv = (wi == 4) || (wi == 5);
  const int ilv_add = (wi == 5) ? 16 : 0;

  float s = 0.f;
  for (int i = blockIdx.x * 256 + t; i < n4; i += 256 * 256) {
    f32x4 v = ((const f32x4*)w)[i];
    u16x4 o;
#pragma unroll
    for (int j = 0; j < 4; ++j) {
      float f = v[j];
      o[j] = f > 0.f ? (u16)0x3F80 : (f < 0.f ? (u16)0xBF80 : (u16)0);
      s += fabsf(f);
    }
    size_t di = i;
    if (ilv) {
      int e = i << 2;                 // element index
      int row = e >> 10, col = e & 1023;
      int dst = ((row >> 4) << 5) + ilv_add + (row & 15);
      di = ((size_t)dst << 8) + (col >> 2);
    }
    ((u16x4*)sgn)[di] = o;
  }
#pragma unroll
  for (int off = 32; off >= 1; off >>= 1) s += __shfl_xor(s, off);
  if ((t & 63) == 0) red[t >> 6] = s;
  __syncthreads();
  if (t == 0)
    partial[wi * 256 + blockIdx.x] = red[0] + red[1] + red[2] + red[3];
}

__global__ __launch_bounds__(256) void finalize_alpha(
    const float* __restrict__ partial, float* __restrict__ alphas) {
  __shared__ float red[4];
  int wi = blockIdx.x;  // 0..6
  float v = partial[wi * 256 + threadIdx.x];
#pragma unroll
  for (int off = 32; off >= 1; off >>= 1) v += __shfl_xor(v, off);
  if ((threadIdx.x & 63) == 0) red[threadIdx.x >> 6] = v;
  __syncthreads();
  if (threadIdx.x == 0)
    alphas[wi] = (red[0] + red[1] + red[2] + red[3]) *
                 (wi < 4 ? (1.f / 1048576.f) : (1.f / 4194304.f));
}

// ---------------------------------------------------------------------------
// RMSNorm + act_quant (group 64). One block per row of 1024.  (FFN branch)
// ---------------------------------------------------------------------------
__global__ __launch_bounds__(256) void rmsnorm_quant(
    const float* __restrict__ x, const float* __restrict__ g, u16* __restrict__ out) {
  __shared__ float red[4];
  const int row = blockIdx.x, t = threadIdx.x;
  f32x4 v = ((const f32x4*)(x + (size_t)row * 1024))[t];
  float ss = v[0] * v[0] + v[1] * v[1] + v[2] * v[2] + v[3] * v[3];
#pragma unroll
  for (int off = 32; off >= 1; off >>= 1) ss += __shfl_xor(ss, off);
  if ((t & 63) == 0) red[t >> 6] = ss;
  __syncthreads();
  float tot = red[0] + red[1] + red[2] + red[3];
  float rinv = rsqrtf(tot * (1.f / 1024.f) + 1e-6f);
  f32x4 gg = ((const f32x4*)g)[t];
  float n[4];
#pragma unroll
  for (int j = 0; j < 4; ++j) n[j] = v[j] * rinv * gg[j];
  float gm = fmaxf(fmaxf(fabsf(n[0]), fabsf(n[1])), fmaxf(fabsf(n[2]), fabsf(n[3])));
#pragma unroll
  for (int off = 1; off <= 8; off <<= 1) gm = fmaxf(gm, __shfl_xor(gm, off));
  float s = fmaxf(gm, 1e-5f) / 127.0f;
  u16x4 o;
#pragma unroll
  for (int j = 0; j < 4; ++j) {
    float q = fminf(fmaxf(rintf(n[j] / s), -127.f), 127.f) * s;
    o[j] = f2bf(q);
  }
  ((u16x4*)out)[(size_t)row * 256 + t] = o;
}

// ---------------------------------------------------------------------------
// V transpose: qkv[:,2048+h*64 .. +63] -> Vt[h][d][t]  ([16][64][4096] bf16).
// ---------------------------------------------------------------------------
__global__ __launch_bounds__(256) void transpose_v(
    const u16* __restrict__ qkv, u16* __restrict__ Vt) {
  __shared__ u16 T[64][65];
  const int tt = blockIdx.x, h = blockIdx.y, tid = threadIdx.x;
#pragma unroll
  for (int i = 0; i < 2; ++i) {
    int idx = i * 2048 + tid * 8;
    int trow = idx >> 6, dcol = idx & 63;
    u16x8 v = *(const u16x8*)(qkv + (size_t)(tt * 64 + trow) * 3072 + 2048 + h * 64 + dcol);
#pragma unroll
    for (int j = 0; j < 8; ++j) T[dcol + j][trow] = v[j];
  }
  __syncthreads();
#pragma unroll
  for (int i = 0; i < 2; ++i) {
    int idx = i * 2048 + tid * 8;
    int drow = idx >> 6, tcol = idx & 63;
    u16x8 v;
#pragma unroll
    for (int j = 0; j < 8; ++j) v[j] = T[drow][tcol + j];
    *(u16x8*)(Vt + ((size_t)h * 64 + drow) * 4096 + tt * 64 + tcol) = v;
  }
}

// ---------------------------------------------------------------------------
// GEMM: C[M,N] = alpha[bcol>>ashift] * (A[M,K] @ B[N,K]^T) (+res).
// BMx128 tile, BK=64, 4 waves, global_load_lds w=16, XOR swizzle.
// ---------------------------------------------------------------------------
template <bool RES, int BM>
__global__ __launch_bounds__(256) void gemm_bt(
    const u16* __restrict__ A, const u16* __restrict__ B,
    const float* __restrict__ alpha, int ashift, const float* __restrict__ res,
    void* __restrict__ Cout, int M, int N, int K) {
  constexpr int NI = (BM == 128) ? 4 : 2;
  constexpr int WNE = (BM == 128) ? 64 : 32;
  __shared__ u16 As[BM * 64];
  __shared__ u16 Bs[128 * 64];
  const int tid = threadIdx.x;
  const int l = tid & 63, w = tid >> 6;
  const int wm = (BM == 128) ? (w >> 1) : 0;
  const int wn = (BM == 128) ? (w & 1) : w;
  const int lr = l & 15, lg = l >> 4;
  const int xorv = (l & 7) << 4;
  const int brow = blockIdx.y * BM;
  const int bcol = blockIdx.x * 128;
  const int src_chunk = (l & 7) ^ (l >> 3);
  const int rl = w * 8 + (l >> 3);

  f32x4 acc[4][NI];
#pragma unroll
  for (int i = 0; i < 4; ++i)
#pragma unroll
    for (int j = 0; j < NI; ++j) acc[i][j] = (f32x4){0.f, 0.f, 0.f, 0.f};

  const char* Ag = (const char*)A;
  const char* Bg = (const char*)B;
  const int nkt = K >> 6;
  for (int kt = 0; kt < nkt; ++kt) {
    __syncthreads();
    const size_t kb = (size_t)kt * 128 + src_chunk * 16;
#pragma unroll
    for (int it = 0; it < BM / 32; ++it)
      gload16(Ag + (size_t)(brow + it * 32 + rl) * (size_t)(K * 2) + kb,
              &As[(it * 32 + w * 8) * 64]);
#pragma unroll
    for (int it = 0; it < 4; ++it)
      gload16(Bg + (size_t)(bcol + it * 32 + rl) * (size_t)(K * 2) + kb,
              &Bs[(it * 32 + w * 8) * 64]);
    __syncthreads();

    bf16x8 af[4][2], bfr[NI][2];
#pragma unroll
    for (int mi = 0; mi < 4; ++mi)
#pragma unroll
      for (int ks = 0; ks < 2; ++ks) {
        int row = wm * 64 + mi * 16 + lr;
        af[mi][ks] = *(const bf16x8*)((const char*)As + row * 128 + ((ks * 64 + lg * 16) ^ xorv));
      }
#pragma unroll
    for (int ni = 0; ni < NI; ++ni)
#pragma unroll
      for (int ks = 0; ks < 2; ++ks) {
        int row = wn * WNE + ni * 16 + lr;
        bfr[ni][ks] = *(const bf16x8*)((const char*)Bs + row * 128 + ((ks * 64 + lg * 16) ^ xorv));
      }
#pragma unroll
    for (int ks = 0; ks < 2; ++ks)
#pragma unroll
      for (int mi = 0; mi < 4; ++mi)
#pragma unroll
        for (int ni = 0; ni < NI; ++ni)
          acc[mi][ni] = __builtin_amdgcn_mfma_f32_16x16x32_bf16(
              af[mi][ks], bfr[ni][ks], acc[mi][ni], 0, 0, 0);
  }

  const float scale = alpha[bcol >> ashift];
#pragma unroll
  for (int mi = 0; mi < 4; ++mi)
#pragma unroll
    for (int ni = 0; ni < NI; ++ni)
#pragma unroll
      for (int r = 0; r < 4; ++r) {
        int row = brow + wm * 64 + mi * 16 + lg * 4 + r;
        int col = bcol + wn * WNE + ni * 16 + lr;
        float vv = acc[mi][ni][r] * scale;
        if (RES)
          ((float*)Cout)[(size_t)row * N + col] = res[(size_t)row * N + col] + vv;
        else
          ((u16*)Cout)[(size_t)row * N + col] = f2bf(vv);
      }
}

// ---------------------------------------------------------------------------
// Fat-wave GEMM: 256(M) x 128(N) tile, 4 waves, per-wave 128x64 output.
// 24 LDS reads / 64 MFMA per wave-iter. Used for the QKV projection.
// ---------------------------------------------------------------------------
template <bool RES>
__global__ __launch_bounds__(256, 2) void gemm_fat(
    const u16* __restrict__ A, const u16* __restrict__ B,
    const float* __restrict__ alpha, int ashift, const float* __restrict__ res,
    void* __restrict__ Cout, int M, int N, int K) {
  __shared__ u16 As[256 * 64];  // 32KB
  __shared__ u16 Bs[128 * 64];  // 16KB
  const int tid = threadIdx.x;
  const int l = tid & 63, w = tid >> 6;
  const int wm = w >> 1, wn = w & 1;
  const int lr = l & 15, lg = l >> 4;
  const int xorv = (l & 7) << 4;
  const int brow = blockIdx.y * 256;
  const int bcol = blockIdx.x * 128;
  const int src_chunk = (l & 7) ^ (l >> 3);
  const int rl = w * 8 + (l >> 3);

  f32x4 acc[8][4];
#pragma unroll
  for (int i = 0; i < 8; ++i)
#pragma unroll
    for (int j = 0; j < 4; ++j) acc[i][j] = (f32x4){0.f, 0.f, 0.f, 0.f};

  const int nkt = K >> 6;
  for (int kt = 0; kt < nkt; ++kt) {
    __syncthreads();
    const size_t kb = (size_t)kt * 128 + src_chunk * 16;
#pragma unroll
    for (int it = 0; it < 8; ++it)
      gload16((const char*)A + (size_t)(brow + it * 32 + rl) * (size_t)(K * 2) + kb,
              &As[(it * 32 + w * 8) * 64]);
#pragma unroll
    for (int it = 0; it < 4; ++it)
      gload16((const char*)B + (size_t)(bcol + it * 32 + rl) * (size_t)(K * 2) + kb,
              &Bs[(it * 32 + w * 8) * 64]);
    __syncthreads();

#pragma unroll
    for (int ks = 0; ks < 2; ++ks) {
      bf16x8 bfr[4];
#pragma unroll
      for (int ni = 0; ni < 4; ++ni)
        bfr[ni] = *(const bf16x8*)((const char*)Bs + (wn * 64 + ni * 16 + lr) * 128 +
                                   ((ks * 64 + lg * 16) ^ xorv));
#pragma unroll
      for (int mi = 0; mi < 8; ++mi) {
        bf16x8 af = *(const bf16x8*)((const char*)As + (wm * 128 + mi * 16 + lr) * 128 +
                                     ((ks * 64 + lg * 16) ^ xorv));
#pragma unroll
        for (int ni = 0; ni < 4; ++ni)
          acc[mi][ni] = __builtin_amdgcn_mfma_f32_16x16x32_bf16(
              af, bfr[ni], acc[mi][ni], 0, 0, 0);
      }
    }
  }

  const float scale = alpha[bcol >> ashift];
#pragma unroll
  for (int mi = 0; mi < 8; ++mi)
#pragma unroll
    for (int ni = 0; ni < 4; ++ni)
#pragma unroll
      for (int r = 0; r < 4; ++r) {
        int row = brow + wm * 128 + mi * 16 + lg * 4 + r;
        int col = bcol + wn * 64 + ni * 16 + lr;
        float vv = acc[mi][ni][r] * scale;
        if (RES)
          ((float*)Cout)[(size_t)row * N + col] = res[(size_t)row * N + col] + vv;
        else
          ((u16*)Cout)[(size_t)row * N + col] = f2bf(vv);
      }
}

// ---------------------------------------------------------------------------
// Fused FFN GEMM, fat-wave: tile 256(M) x 128(W12 rows = 64 z-cols),
// 4 waves, per-wave output 128x64 (acc 8x4). W12 fine-interleaved (16-row).
// ---------------------------------------------------------------------------
__global__ __launch_bounds__(256, 2) void gemm_ffn(
    const u16* __restrict__ A, const u16* __restrict__ B12,
    const float* __restrict__ alpha2, u16* __restrict__ zq) {
  __shared__ u16 As[256 * 64];  // 32KB
  __shared__ u16 Bs[128 * 64];  // 16KB
  const int tid = threadIdx.x;
  const int l = tid & 63, w = tid >> 6;
  const int wm = w >> 1, wn = w & 1;
  const int lr = l & 15, lg = l >> 4;
  const int xorv = (l & 7) << 4;
  const int brow = blockIdx.y * 256;
  const int bcol = blockIdx.x * 128;  // W12 row block = 64 z-cols
  const int src_chunk = (l & 7) ^ (l >> 3);
  const int rl = w * 8 + (l >> 3);

  f32x4 acc[8][4];
#pragma unroll
  for (int i = 0; i < 8; ++i)
#pragma unroll
    for (int j = 0; j < 4; ++j) acc[i][j] = (f32x4){0.f, 0.f, 0.f, 0.f};

  for (int kt = 0; kt < 16; ++kt) {
    __syncthreads();
    const size_t kb = (size_t)kt * 128 + src_chunk * 16;
#pragma unroll
    for (int it = 0; it < 8; ++it)
      gload16((const char*)A + (size_t)(brow + it * 32 + rl) * 2048 + kb,
              &As[(it * 32 + w * 8) * 64]);
#pragma unroll
    for (int it = 0; it < 4; ++it)
      gload16((const char*)B12 + (size_t)(bcol + it * 32 + rl) * 2048 + kb,
              &Bs[(it * 32 + w * 8) * 64]);
    __syncthreads();

#pragma unroll
    for (int ks = 0; ks < 2; ++ks) {
      bf16x8 bfr[4];
#pragma unroll
      for (int ni = 0; ni < 4; ++ni)
        bfr[ni] = *(const bf16x8*)((const char*)Bs + (wn * 64 + ni * 16 + lr) * 128 +
                                   ((ks * 64 + lg * 16) ^ xorv));
#pragma unroll
      for (int mi = 0; mi < 8; ++mi) {
        bf16x8 af = *(const bf16x8*)((const char*)As + (wm * 128 + mi * 16 + lr) * 128 +
                                     ((ks * 64 + lg * 16) ^ xorv));
#pragma unroll
        for (int ni = 0; ni < 4; ++ni)
          acc[mi][ni] = __builtin_amdgcn_mfma_f32_16x16x32_bf16(
              af, bfr[ni], acc[mi][ni], 0, 0, 0);
      }
    }
  }

  // ---- epilogue: z = silu(a1*y1)*(a2*y2) in-register ----
  const float a1 = alpha2[0], a2 = alpha2[1];
  const float L2E = 1.4426950408889634f;
  float zl[8][4], zh[8][4], rm[8][4];
#pragma unroll
  for (int mi = 0; mi < 8; ++mi)
#pragma unroll
    for (int r = 0; r < 4; ++r) {
      float y1 = acc[mi][0][r] * a1;
      zl[mi][r] = y1 / (1.f + fexp2(-L2E * y1)) * (acc[mi][1][r] * a2);
      float y3 = acc[mi][2][r] * a1;
      zh[mi][r] = y3 / (1.f + fexp2(-L2E * y3)) * (acc[mi][3][r] * a2);
      float g = fmaxf(fabsf(zl[mi][r]), fabsf(zh[mi][r]));
#pragma unroll
      for (int off = 1; off <= 8; off <<= 1) g = fmaxf(g, __shfl_xor(g, off));
      rm[mi][r] = g;  // this wave's 32-col max for the row
    }

  // cross-wave (wn pair: w and w^1 share wm) row-max via aliased staging LDS
  float* rmax = (float*)&As[0];  // [4][128] f32 = 2KB
  __syncthreads();               // all waves done reading staging
  if (lr == 0) {
#pragma unroll
    for (int mi = 0; mi < 8; ++mi)
#pragma unroll
      for (int r = 0; r < 4; ++r)
        rmax[w * 128 + mi * 16 + lg * 4 + r] = rm[mi][r];
  }
  __syncthreads();

#pragma unroll
  for (int mi = 0; mi < 8; ++mi)
#pragma unroll
    for (int r = 0; r < 4; ++r) {
      float g = fmaxf(rm[mi][r], rmax[(w ^ 1) * 128 + mi * 16 + lg * 4 + r]);
      float gmc = fmaxf(g, 1e-5f);
      float s = gmc * (1.f / 127.f);
      float inv = 127.f / gmc;
      int row = brow + wm * 128 + mi * 16 + lg * 4 + r;
      int zc = blockIdx.x * 64 + wn * 32 + lr;
      float q0 = fminf(fmaxf(rintf(zl[mi][r] * inv), -127.f), 127.f) * s;
      float q1 = fminf(fmaxf(rintf(zh[mi][r] * inv), -127.f), 127.f) * s;
      zq[(size_t)row * 4096 + zc] = f2bf(q0);
      zq[(size_t)row * 4096 + zc + 16] = f2bf(q1);
    }
}

// ---------------------------------------------------------------------------
// Causal flash attention + act_quant.  SWAPPED-OPERAND form, 8 waves.
// QBLK=128 (8 waves x 16 q-rows): one staged 64-tok K/V tile serves 8 waves.
// Grid (16 heads, 32 q-tiles): qt = y<16?y:47-y -> every CU gets 2 blocks
// totalling exactly 66 k-iters under stride-256 round-robin.
// VALU diet: exp2(fma(S,SC,-m)) (max on raw S), cvt_pk bf16 P-pack.
// ---------------------------------------------------------------------------
__global__ __launch_bounds__(512) void attn_kernel(
    const u16* __restrict__ QKV, const u16* __restrict__ Vt, u16* __restrict__ Y) {
  __shared__ u16 Ks[2][64 * 64];  // [k-token 64][d 64] swizzled, 16KB
  __shared__ u16 Vs[2][64 * 64];  // [d 64][k-token 64] swizzled, 16KB
  __shared__ u16 Ps[8][16 * 64];  // per-wave P^T [q 16][token 64], 16KB

  const int tid = threadIdx.x;
  const int l = tid & 63, w = tid >> 6;  // w in 0..7
  const int lr = l & 15, lg = l >> 4;
  const int xorv = (l & 7) << 4;
  const int h = blockIdx.x;
  const int y = blockIdx.y;
  const int qt = (y < 16) ? y : (47 - y);  // 128-row q-tile index, 0..31
  const int src_chunk = (l & 7) ^ (l >> 3);
  const int rl = w * 8 + (l >> 3);         // 0..63 across 8 waves
  const float SC = 0.18033688f;            // 0.125 * log2(e)

  const int qrow0 = qt * 128 + w * 16;     // this wave's first q row
  const int nkt = 2 * qt + 2;

  bf16x8 qf[2];
#pragma unroll
  for (int ks = 0; ks < 2; ++ks)
    qf[ks] = __builtin_bit_cast(
        bf16x8, *(const u16x8*)(QKV + (size_t)(qrow0 + lr) * 3072 +
                                h * 64 + ks * 32 + lg * 8));

  f32x4 O[4];  // O^T: lane holds O[q=lr][d = ni*16 + lg*4 + r]
#pragma unroll
  for (int ni = 0; ni < 4; ++ni) O[ni] = (f32x4){0.f, 0.f, 0.f, 0.f};
  float m_ = -3e38f, lsum = 0.f;

  auto STAGE = [&](int buf, int kt) {
    // 8 waves x 8 rows: one K row-group + one V row-group per wave
    int krow = kt * 64 + rl;
    gload16((const char*)QKV + ((size_t)krow * 3072 + 1024 + h * 64) * 2 + src_chunk * 16,
            &Ks[buf][(w * 8) * 64]);
    gload16((const char*)Vt + (((size_t)h * 64 + rl) * 4096 + kt * 64) * 2 + src_chunk * 16,
            &Vs[buf][(w * 8) * 64]);
  };

  STAGE(0, 0);
#pragma unroll 1
  for (int kt = 0; kt < nkt; ++kt) {
    const int cur = kt & 1;
    if (kt + 1 < nkt) {
      STAGE(cur ^ 1, kt + 1);
      asm volatile("s_waitcnt vmcnt(2)" ::: "memory");  // cur tile's 2 done
    } else {
      asm volatile("s_waitcnt vmcnt(0)" ::: "memory");
    }
    __builtin_amdgcn_s_barrier();
    __builtin_amdgcn_sched_barrier(0);

    const char* kbase = (const char*)&Ks[cur][0];
    const char* vbase = (const char*)&Vs[cur][0];

    // S^T[ni] = mfma(K, Q)  (raw, unscaled)
    f32x4 S[4];
    __builtin_amdgcn_s_setprio(1);
#pragma unroll
    for (int ni = 0; ni < 4; ++ni) {
      S[ni] = (f32x4){0.f, 0.f, 0.f, 0.f};
#pragma unroll
      for (int ks = 0; ks < 2; ++ks) {
        bf16x8 kf = *(const bf16x8*)(kbase + (ni * 16 + lr) * 128 +
                                     ((ks * 64 + lg * 16) ^ xorv));
        S[ni] = __builtin_amdgcn_mfma_f32_16x16x32_bf16(kf, qf[ks], S[ni], 0, 0, 0);
      }
    }
    __builtin_amdgcn_s_setprio(0);

    // causal mask on raw S (only tiles whose max token reaches this wave's q)
    const int tb = kt * 64;
    if (tb + 63 > qrow0) {
#pragma unroll
      for (int ni = 0; ni < 4; ++ni)
#pragma unroll
        for (int r = 0; r < 4; ++r)
          if (tb + ni * 16 + lg * 4 + r > qrow0 + lr) S[ni][r] = -3e38f;
    }

    // online softmax (lane owns its q-row). Max on RAW S, scale folds to fma.
    float nm = -3e38f;
#pragma unroll
    for (int ni = 0; ni < 4; ++ni)
#pragma unroll
      for (int r = 0; r < 4; ++r) nm = fmaxf(nm, S[ni][r]);
    nm = fmaxf(nm, __shfl_xor(nm, 16));
    nm = fmaxf(nm, __shfl_xor(nm, 32));
    float nms = nm * SC;
    if (__ballot(nms > m_ + 8.f)) {  // T13 defer-rescale
      float mn = fmaxf(m_, nms);
      float fac = fexp2(m_ - mn);
      m_ = mn;
      lsum *= fac;
#pragma unroll
      for (int ni = 0; ni < 4; ++ni) O[ni] *= fac;
    }
    float rs = 0.f;
#pragma unroll
    for (int ni = 0; ni < 4; ++ni)
#pragma unroll
      for (int r = 0; r < 4; ++r) {
        float pv = fexp2(__builtin_fmaf(S[ni][r], SC, -m_));
        S[ni][r] = pv;
        rs += pv;
      }
    rs += __shfl_xor(rs, 16);
    rs += __shfl_xor(rs, 32);
    lsum += rs;

    // P^T -> per-wave LDS via cvt_pk (2 u32 per ni), packed b64
#pragma unroll
    for (int ni = 0; ni < 4; ++ni) {
      u32x2 pk;
      pk[0] = cvtpk(S[ni][0], S[ni][1]);
      pk[1] = cvtpk(S[ni][2], S[ni][3]);
      *(u32x2*)((char*)&Ps[w][0] + lr * 128 + ((ni * 32 + lg * 8) ^ xorv)) = pk;
    }
    bf16x8 pt[2];
#pragma unroll
    for (int ks = 0; ks < 2; ++ks)
      pt[ks] = *(const bf16x8*)((const char*)&Ps[w][0] + lr * 128 +
                                ((ks * 64 + lg * 16) ^ xorv));

    // O^T[ni] += mfma(V^T, P^T)
    __builtin_amdgcn_s_setprio(1);
#pragma unroll
    for (int ni = 0; ni < 4; ++ni) {
#pragma unroll
      for (int ks = 0; ks < 2; ++ks) {
        bf16x8 vf = *(const bf16x8*)(vbase + (ni * 16 + lr) * 128 +
                                     ((ks * 64 + lg * 16) ^ xorv));
        O[ni] = __builtin_amdgcn_mfma_f32_16x16x32_bf16(vf, pt[ks], O[ni], 0, 0, 0);
      }
    }
    __builtin_amdgcn_s_setprio(0);
    asm volatile("" ::: "memory");
    __builtin_amdgcn_s_barrier();
  }

  // epilogue: normalize + act_quant (group of 64 = this head's dims)
  float rinv = 1.f / lsum;
  float o[4][4];
  float gm = 0.f;
#pragma unroll
  for (int ni = 0; ni < 4; ++ni)
#pragma unroll
    for (int r = 0; r < 4; ++r) {
      o[ni][r] = O[ni][r] * rinv;
      gm = fmaxf(gm, fabsf(o[ni][r]));
    }
  gm = fmaxf(gm, __shfl_xor(gm, 16));
  gm = fmaxf(gm, __shfl_xor(gm, 32));
  float gmc = fmaxf(gm, 1e-5f);
  float s = gmc * (1.f / 127.f);
  float inv = 127.f / gmc;
#pragma unroll
  for (int ni = 0; ni < 4; ++ni) {
    u16x4 ov;
#pragma unroll
    for (int r = 0; r < 4; ++r) {
      float q = fminf(fmaxf(rintf(o[ni][r] * inv), -127.f), 127.f) * s;
      ov[r] = f2bf(q);
    }
    *(u16x4*)(Y + (size_t)(qrow0 + lr) * 1024 + h * 64 + ni * 16 + lg * 4) = ov;
  }
}

// ---------------------------------------------------------------------------
extern "C" void kernel_launch(void* const* d_in, const int* in_sizes, int n_in,
                              void* d_out, int out_size, void* d_ws, size_t ws_size,
                              hipStream_t stream) {
  const float* x  = (const float*)d_in[0];
  const float* wq = (const float*)d_in[1];
  const float* wk = (const float*)d_in[2];
  const float* wv = (const float*)d_in[3];
  const float* wo = (const float*)d_in[4];
  const float* w1 = (const float*)d_in[5];
  const float* w2 = (const float*)d_in[6];
  const float* w3 = (const float*)d_in[7];
  const float* g1 = (const float*)d_in[8];
  const float* g2 = (const float*)d_in[9];

  char* ws = (char*)d_ws;
  const size_t MB = 1024 * 1024;
  u16* sgn   = (u16*)ws;
  u16* sWq   = (u16*)(ws + 0 * MB);
  u16* sWo   = (u16*)(ws + 6 * MB);
  u16* sW12  = (u16*)(ws + 8 * MB);    // fine-interleaved [8192,1024]
  u16* sW3   = (u16*)(ws + 24 * MB);
  float* partial = (float*)(ws + 32 * MB);
  float* alphas  = (float*)(ws + 32 * MB + 16384);
  u16* Vt    = (u16*)(ws + 33 * MB);   // dead before x1 written
  float* x1  = (float*)(ws + 33 * MB); // fp32 [4096,1024]
  u16* hq    = (u16*)(ws + 49 * MB);   // bf16 [4096,1024]
  u16* qkv   = (u16*)(ws + 57 * MB);   // bf16 [4096,3072]
  u16* yb    = (u16*)(ws + 81 * MB);   // bf16 [4096,1024]
  u16* zq    = (u16*)(ws + 57 * MB);   // bf16 [4096,4096] (qkv,yb dead)

  // weight prep + rmsnorm#1 (y==7) fused
  convert_sign_all<<<dim3(256, 8), 256, 0, stream>>>(wq, wk, wv, wo, w1, w2, w3,
                                                     sgn, partial, x, g1, hq);
  finalize_alpha<<<7, 256, 0, stream>>>(partial, alphas);

  // attention branch
  gemm_fat<false><<<dim3(24, 16), 256, 0, stream>>>(hq, sWq, alphas, 10, nullptr,
                                                    qkv, 4096, 3072, 1024);
  transpose_v<<<dim3(64, 16), 256, 0, stream>>>(qkv, Vt);
  attn_kernel<<<dim3(16, 32), 512, 0, stream>>>(qkv, Vt, yb);
  gemm_bt<true, 64><<<dim3(8, 64), 256, 0, stream>>>(yb, sWo, alphas + 3, 31, x,
                                                     x1, 4096, 1024, 1024);
  // FFN branch
  rmsnorm_quant<<<4096, 256, 0, stream>>>(x1, g2, hq);
  gemm_ffn<<<dim3(64, 16), 256, 0, stream>>>(hq, sW12, alphas + 4, zq);
  gemm_bt<true, 64><<<dim3(8, 64), 256, 0, stream>>>(zq, sW3, alphas + 6, 31, x1,
                                                     (float*)d_out, 4096, 1024, 4096);
}